// Round 11
// baseline (417.498 us; speedup 1.0000x reference)
//
#include <hip/hip_runtime.h>
#include <stdint.h>

// Sizes (fixed by the problem)
#define NB 256
#define NS 64
#define NR 256
#define NV 2000
#define NC 10
#define NK 6
#define ND 256

typedef __attribute__((ext_vector_type(8))) short bf16x8;
typedef __attribute__((ext_vector_type(4))) float f32x4;

__device__ __forceinline__ float bf2f(uint16_t u) {
  return __uint_as_float(((uint32_t)u) << 16);
}
__device__ __forceinline__ uint16_t f2bf(float f) {
  uint32_t x = __float_as_uint(f);
  x += 0x7FFFu + ((x >> 16) & 1u);
  return (uint16_t)(x >> 16);
}

// ---------------------------------------------------------------------------
// k_front: merged independent preprocessing.
//   blocks 0..10    : k_prep  (adjacency/bitmask/lists/midx + ud2/us2)
//   blocks 11..138  : k_prept (weight transposes to bf16 N-major)
//   blocks 139..394 : k_ruleq (rule embeddings + Q proj, bf16*0.125)
//   blocks 395..2442: k_kvproj (KX/VX = vis @ Wk/Wv + bias, MFMA)
// ---------------------------------------------------------------------------
__global__ __launch_bounds__(256) void k_front(
    const void* __restrict__ adj_raw, const int* __restrict__ mask,
    const float* __restrict__ W2, const float* __restrict__ a2s,
    const float* __restrict__ a2d,
    uint32_t* __restrict__ adjbits, int* __restrict__ cls,
    int* __restrict__ lists, int* __restrict__ cnt,
    int* __restrict__ deg, uint8_t* __restrict__ nbr,
    int8_t* __restrict__ midx,
    float* __restrict__ ud2, float* __restrict__ us2,
    const float* __restrict__ Wo, const float* __restrict__ Wk,
    const float* __restrict__ Wv, const float* __restrict__ W1,
    uint16_t* __restrict__ WOT, uint16_t* __restrict__ WKVT,
    uint16_t* __restrict__ W1T,
    const float* __restrict__ basic, const float* __restrict__ cruc,
    const float* __restrict__ Wtb, const float* __restrict__ btb,
    const float* __restrict__ Wtk, const float* __restrict__ btk,
    const float* __restrict__ Wq, const float* __restrict__ bq,
    uint16_t* __restrict__ Qbf,
    const float* __restrict__ vis, const float* __restrict__ bk,
    const float* __restrict__ bv,
    uint16_t* __restrict__ KX, uint16_t* __restrict__ VX)
{
  __shared__ char smem[33792];
  int bid = blockIdx.x;
  int tid = threadIdx.x;
  if (bid < 11) {
    // ---- k_prep ----
    if (bid == 0) {
      int* s_is4 = (int*)smem;
      if (tid == 0) *s_is4 = 1;
      __syncthreads();
      const uint32_t* u = (const uint32_t*)adj_raw;
      int ok = 1;
      for (int idx = tid; idx < 16384; idx += 256) {
        uint32_t v = u[idx];
        if (!(v == 0u || v == 1u || v == 0x3F800000u)) ok = 0;
      }
      if (!ok) atomicAnd(s_is4, 0);
      __syncthreads();
      int is4 = *s_is4;
      const uint8_t* b8 = (const uint8_t*)adj_raw;
      int dg = 0;
      for (int w = 0; w < 8; ++w) {
        uint32_t word = 0;
        for (int jb = 0; jb < 32; ++jb) {
          int j = w * 32 + jb;
          int bit = is4 ? (u[tid * 256 + j] != 0u) : (b8[tid * 256 + j] != 0);
          if (bit) {
            word |= (1u << jb);
            if (dg < 64) nbr[tid * 64 + dg] = (uint8_t)j;
            dg++;
          }
        }
        adjbits[tid * 8 + w] = word;
      }
      deg[tid] = (dg > 64) ? 64 : dg;
      int c = 0;
      for (int cc = 0; cc < NC; ++cc) if (mask[cc * 256 + tid] != 0) c = cc;
      cls[tid] = c;
      __syncthreads();
      if (tid == 0) {
        int cn[NC];
        for (int i = 0; i < NC; ++i) cn[i] = 0;
        for (int r = 0; r < 256; ++r) {
          int cc = cls[r];
          if (cn[cc] < 64) lists[cc * 64 + cn[cc]] = r;
          cn[cc]++;
        }
        for (int i = 0; i < NC; ++i) cnt[i] = (cn[i] > 64) ? 64 : cn[i];
        for (int i = 0; i < NC * 256; ++i) midx[i] = -1;
        for (int cc = 0; cc < NC; ++cc)
          for (int i = 0; i < cnt[cc]; ++i)
            midx[cc * 256 + lists[cc * 64 + i]] = (int8_t)i;
      }
    } else {
      int c = bid - 1;
      if (tid < 128) {
        float s1 = 0.f, s2 = 0.f;
        for (int g = 0; g < 64; ++g) {
          float w = W2[(c * 128 + tid) * 64 + g];
          s1 += w * a2d[c * 64 + g];
          s2 += w * a2s[c * 64 + g];
        }
        ud2[c * 128 + tid] = s1;
        us2[c * 128 + tid] = s2;
      }
    }
  } else if (bid < 139) {
    // ---- k_prept ----
    float (*ts)[65] = (float(*)[65])smem;
    int pb = bid - 11;
    const float* src;
    uint16_t* dst;
    int ncols, kt, nt;
    if (pb < 16)      { src = Wo; dst = WOT; ncols = 256; kt = pb >> 2; nt = pb & 3; }
    else if (pb < 32) { int t = pb - 16; src = Wk; dst = WKVT; ncols = 256; kt = t >> 2; nt = t & 3; }
    else if (pb < 48) { int t = pb - 32; src = Wv; dst = WKVT + 256 * 256; ncols = 256; kt = t >> 2; nt = t & 3; }
    else { int t = pb - 48; int c = t >> 3; int tt = t & 7;
           src = W1 + (long)c * 256 * 128; dst = W1T + (long)c * 128 * 256;
           ncols = 128; kt = tt >> 1; nt = tt & 1; }
    for (int idx = tid; idx < 4096; idx += 256) {
      int i = idx >> 6, j = idx & 63;
      ts[i][j] = src[(long)(kt * 64 + i) * ncols + nt * 64 + j];
    }
    __syncthreads();
    for (int idx = tid; idx < 4096; idx += 256) {
      int i = idx >> 6, j = idx & 63;
      dst[(long)(nt * 64 + i) * 256 + kt * 64 + j] = f2bf(ts[j][i]);
    }
  } else if (bid < 395) {
    // ---- k_ruleq ----
    float* row_s  = (float*)smem;              // 2048 f
    float* rule_s = row_s + 2048;              // 256 f
    int*   nzi    = (int*)(rule_s + 256);      // 128 i
    float* nzv    = (float*)(nzi + 128);       // 128 f
    int*   nzcp   = (int*)(nzv + 128);         // 1 i
    int r = bid - 139;
    float acc = btb[tid] + btk[tid];
    for (int m = 0; m < 2; ++m) {
      const float* src = m ? cruc : basic;
      const float* W   = m ? Wtk : Wtb;
      for (int idx = tid; idx < 2048; idx += 256)
        row_s[idx] = (idx < NV) ? src[r * NV + idx] : 0.0f;
      if (tid == 0) *nzcp = 0;
      __syncthreads();
      if (tid < 64) {
        int base = 0;
        for (int ch = 0; ch < 32; ++ch) {
          int idx = ch * 64 + tid;
          float v = row_s[idx];
          unsigned long long bm = __ballot(v != 0.0f);
          if (v != 0.0f) {
            int pos = base + (int)__popcll(bm & ((1ull << tid) - 1ull));
            if (pos < 128) { nzi[pos] = idx; nzv[pos] = v; }
          }
          base += (int)__popcll(bm);
        }
        if (tid == 0) *nzcp = (base > 128) ? 128 : base;
      }
      __syncthreads();
      int n = *nzcp;
      for (int t = 0; t < n; ++t) acc += nzv[t] * W[nzi[t] * 256 + tid];
      __syncthreads();
    }
    rule_s[tid] = acc;
    __syncthreads();
    float q = bq[tid];
    for (int k2 = 0; k2 < 256; ++k2) q += rule_s[k2] * Wq[k2 * 256 + tid];
    Qbf[r * 256 + tid] = f2bf(q * 0.125f);
  } else {
    // ---- k_kvproj ----
    uint16_t* A_s = (uint16_t*)smem;  // 64 x 264
    int t = bid - 395;
    int bx = t & 255, by = t >> 8;
    int lane = tid & 63, w = tid >> 6;
    int r15 = lane & 15, kg = lane >> 4;
    long m0 = (long)bx * 64;
    int n0 = by * 64 + w * 16;
    for (int idx = tid; idx < 2048; idx += 256) {
      int r = idx >> 5, ch = idx & 31;
      const float4* p = (const float4*)&vis[(m0 + r) * 256 + ch * 8];
      float4 v0 = p[0], v1 = p[1];
      uint4 wd;
      wd.x = (uint32_t)f2bf(v0.x) | ((uint32_t)f2bf(v0.y) << 16);
      wd.y = (uint32_t)f2bf(v0.z) | ((uint32_t)f2bf(v0.w) << 16);
      wd.z = (uint32_t)f2bf(v1.x) | ((uint32_t)f2bf(v1.y) << 16);
      wd.w = (uint32_t)f2bf(v1.z) | ((uint32_t)f2bf(v1.w) << 16);
      *(uint4*)&A_s[r * 264 + ch * 8] = wd;
    }
    __syncthreads();
    const uint16_t* bptr = &WKVT[(long)(n0 + r15) * 256 + kg * 8];
    f32x4 acc[4];
    #pragma unroll
    for (int mt = 0; mt < 4; ++mt) acc[mt] = (f32x4){0.f, 0.f, 0.f, 0.f};
    #pragma unroll
    for (int ks = 0; ks < 8; ++ks) {
      bf16x8 bfr = *(const bf16x8*)(bptr + ks * 32);
      #pragma unroll
      for (int mt = 0; mt < 4; ++mt) {
        bf16x8 afr = *(const bf16x8*)&A_s[(mt * 16 + r15) * 264 + kg * 8 + ks * 32];
        acc[mt] = __builtin_amdgcn_mfma_f32_16x16x32_bf16(afr, bfr, acc[mt], 0, 0, 0);
      }
    }
    int col = n0 + r15;
    float bb = (col < 256) ? bk[col] : bv[col - 256];
    uint16_t* outp = (col < 256) ? KX : VX;
    int oc = (col < 256) ? col : col - 256;
    #pragma unroll
    for (int mt = 0; mt < 4; ++mt)
      #pragma unroll
      for (int j = 0; j < 4; ++j) {
        long row = m0 + mt * 16 + kg * 4 + j;
        outp[row * 256 + oc] = f2bf(acc[mt][j] + bb);
      }
  }
}

// ---------------------------------------------------------------------------
// k_attn (MFMA): block = (batch b, half of rules), 512 thr / 8 waves.
// ---------------------------------------------------------------------------
__global__ __launch_bounds__(512) void k_attn(const uint16_t* __restrict__ Qbf,
                         const uint16_t* __restrict__ KX, const uint16_t* __restrict__ VX,
                         uint16_t* __restrict__ EMB)
{
  __shared__ uint16_t p_s[128 * 72];
  __shared__ uint16_t vt_s[64 * 72];
  int tid = threadIdx.x;
  int lane = tid & 63, w = tid >> 6;   // 8 waves
  int r15 = lane & 15, kg = lane >> 4;
  int b = blockIdx.x >> 1;
  int rbase = (blockIdx.x & 1) * 128;
  for (int h = 0; h < 4; ++h) {
    __syncthreads();  // prev head's vt_s reads done
    for (int idx = tid; idx < 2048; idx += 512) {
      int s = idx >> 5, d2 = (idx & 31) * 2;
      uint32_t v = *(const uint32_t*)&VX[((long)(b * 64 + s)) * 256 + h * 64 + d2];
      vt_s[d2 * 72 + s] = (uint16_t)(v & 0xffff);
      vt_s[(d2 + 1) * 72 + s] = (uint16_t)(v >> 16);
    }
    __syncthreads();
    f32x4 sacc[4];
    #pragma unroll
    for (int nt = 0; nt < 4; ++nt) sacc[nt] = (f32x4){0.f, 0.f, 0.f, 0.f};
    #pragma unroll
    for (int ks = 0; ks < 2; ++ks) {
      bf16x8 afr = *(const bf16x8*)&Qbf[(long)(rbase + w * 16 + r15) * 256 + h * 64 + ks * 32 + kg * 8];
      #pragma unroll
      for (int nt = 0; nt < 4; ++nt) {
        bf16x8 bfr = *(const bf16x8*)&KX[((long)(b * 64 + nt * 16 + r15)) * 256 + h * 64 + ks * 32 + kg * 8];
        sacc[nt] = __builtin_amdgcn_mfma_f32_16x16x32_bf16(afr, bfr, sacc[nt], 0, 0, 0);
      }
    }
    #pragma unroll
    for (int j = 0; j < 4; ++j) {
      float m = sacc[0][j];
      #pragma unroll
      for (int nt = 1; nt < 4; ++nt) m = fmaxf(m, sacc[nt][j]);
      m = fmaxf(m, __shfl_xor(m, 1));
      m = fmaxf(m, __shfl_xor(m, 2));
      m = fmaxf(m, __shfl_xor(m, 4));
      m = fmaxf(m, __shfl_xor(m, 8));
      float pv[4];
      float sum = 0.f;
      #pragma unroll
      for (int nt = 0; nt < 4; ++nt) { pv[nt] = __expf(sacc[nt][j] - m); sum += pv[nt]; }
      sum += __shfl_xor(sum, 1);
      sum += __shfl_xor(sum, 2);
      sum += __shfl_xor(sum, 4);
      sum += __shfl_xor(sum, 8);
      float rs = 1.0f / sum;
      #pragma unroll
      for (int nt = 0; nt < 4; ++nt)
        p_s[(w * 16 + kg * 4 + j) * 72 + nt * 16 + r15] = f2bf(pv[nt] * rs);
    }
    f32x4 oacc[4];
    #pragma unroll
    for (int nt = 0; nt < 4; ++nt) oacc[nt] = (f32x4){0.f, 0.f, 0.f, 0.f};
    #pragma unroll
    for (int ks = 0; ks < 2; ++ks) {
      bf16x8 afr = *(const bf16x8*)&p_s[(w * 16 + r15) * 72 + ks * 32 + kg * 8];
      #pragma unroll
      for (int nt = 0; nt < 4; ++nt) {
        bf16x8 bfr = *(const bf16x8*)&vt_s[(nt * 16 + r15) * 72 + ks * 32 + kg * 8];
        oacc[nt] = __builtin_amdgcn_mfma_f32_16x16x32_bf16(afr, bfr, oacc[nt], 0, 0, 0);
      }
    }
    #pragma unroll
    for (int nt = 0; nt < 4; ++nt)
      #pragma unroll
      for (int j = 0; j < 4; ++j) {
        long row = (long)(b * 256 + rbase + w * 16 + kg * 4 + j);
        EMB[row * 256 + h * 64 + nt * 16 + r15] = f2bf(oacc[nt][j]);
      }
  }
}

// ---------------------------------------------------------------------------
// k_wo (MFMA): EMB = EMB @ Wo + bo, in place (race-free per 64-row block).
// ---------------------------------------------------------------------------
__global__ __launch_bounds__(256) void k_wo(uint16_t* __restrict__ EMB,
                    const uint16_t* __restrict__ WOT, const float* __restrict__ bo)
{
  __shared__ uint16_t A_s[64 * 264];
  int tid = threadIdx.x;
  int lane = tid & 63, w = tid >> 6;
  int r15 = lane & 15, kg = lane >> 4;
  long m0 = (long)blockIdx.x * 64;
  for (int idx = tid; idx < 2048; idx += 256) {
    int r = idx >> 5, ch = idx & 31;
    uint4 v = *(const uint4*)&EMB[(m0 + r) * 256 + ch * 8];
    *(uint4*)&A_s[r * 264 + ch * 8] = v;
  }
  __syncthreads();
  #pragma unroll
  for (int nt = 0; nt < 4; ++nt) {
    int n0 = nt * 64 + w * 16;
    const uint16_t* bptr = &WOT[(long)(n0 + r15) * 256 + kg * 8];
    f32x4 acc[4];
    #pragma unroll
    for (int mt = 0; mt < 4; ++mt) acc[mt] = (f32x4){0.f, 0.f, 0.f, 0.f};
    #pragma unroll
    for (int ks = 0; ks < 8; ++ks) {
      bf16x8 bfr = *(const bf16x8*)(bptr + ks * 32);
      #pragma unroll
      for (int mt = 0; mt < 4; ++mt) {
        bf16x8 afr = *(const bf16x8*)&A_s[(mt * 16 + r15) * 264 + kg * 8 + ks * 32];
        acc[mt] = __builtin_amdgcn_mfma_f32_16x16x32_bf16(afr, bfr, acc[mt], 0, 0, 0);
      }
    }
    int col = n0 + r15;
    float bb = bo[col];
    #pragma unroll
    for (int mt = 0; mt < 4; ++mt)
      #pragma unroll
      for (int j = 0; j < 4; ++j) {
        long row = m0 + mt * 16 + kg * 4 + j;
        EMB[row * 256 + col] = f2bf(acc[mt][j] + bb);
      }
  }
}

// ---------------------------------------------------------------------------
// k_gat v4: fused hw1 + 2x MFMA GAT. LDS < 64KB via aliasing (tpart->alpha,
// pd/ps->e2d/e2s, svec/lvec->hwt, wj->rd1). Neighbor bytes prefetched to
// registers (chunked per q, static word indexing) and reused in all 3
// neighbor phases.
// ---------------------------------------------------------------------------
__global__ __launch_bounds__(1024) void k_gat(
    const uint16_t* __restrict__ EMB, const uint16_t* __restrict__ W1T,
    const float* __restrict__ a1d, const float* __restrict__ a1s,
    const int* __restrict__ lists, const int* __restrict__ cnt_g,
    const int* __restrict__ deg_g, const uint8_t* __restrict__ nbr_g,
    const int8_t* __restrict__ midx_g,
    const float* __restrict__ b1, const float* __restrict__ ud2_g,
    const float* __restrict__ us2_g, const float* __restrict__ W2,
    const float* __restrict__ b2, const float* __restrict__ Wl,
    const float* __restrict__ bl, float* __restrict__ out)
{
  __shared__ uint16_t alpha_s[256 * 72]; // [r][jm] unnorm alpha; later: tpart
  __shared__ uint16_t hwt_s[128 * 72];   // hW1^T [f][jm]; later: svec/lvec
  __shared__ float e1d_s[256], e1s_s[256], rd1_s[256];
  __shared__ float e2d_s[256], e2s_s[256], rd2_s[256];
  __shared__ float a1d_s[128], a1s_s[128], b1_s[128], ud2_s[128], us2_s[128];
  __shared__ float t_s[128];
  __shared__ int   list_s[64];
  float (*tpart)[128] = (float(*)[128])alpha_s;  // alias (alpha dead after P6)
  float* wj_s = rd1_s;                           // alias (rd1 dead after P7)
  float* svec = (float*)hwt_s;                   // alias (hwt dead after P6)
  float* lvec = (float*)(hwt_s + 256);
  int tid = threadIdx.x;
  int lane = tid & 63, w = tid >> 6;
  int r15 = lane & 15, kg = lane >> 4;
  int c = blockIdx.x >> 8, b = blockIdx.x & 255;
  int n = cnt_g[c];
  if (tid < 64) list_s[tid] = (tid < n) ? lists[c * 64 + tid] : 0;
  if (tid < 128) {
    a1d_s[tid] = a1d[c * 128 + tid];
    a1s_s[tid] = a1s[c * 128 + tid];
    b1_s[tid]  = b1[c * 128 + tid];
    ud2_s[tid] = ud2_g[c * 128 + tid];
    us2_s[tid] = us2_g[c * 128 + tid];
  }
  if (tid < 256) { e1d_s[tid] = 0.f; e1s_s[tid] = 0.f; }
  // neighbor chunk prefetch: thread (r,q) owns neighbors [q*16, q*16+16)
  int r = tid >> 2, q = tid & 3;
  int dg = deg_g[r];
  int t0 = q * 16;
  int ncnt = dg - t0; ncnt = (ncnt < 0) ? 0 : (ncnt > 16 ? 16 : ncnt);
  const uint32_t* np = (const uint32_t*)&nbr_g[r * 64 + t0];
  uint32_t nbw0 = np[0], nbw1 = np[1], nbw2 = np[2], nbw3 = np[3];
  __syncthreads();  // B0
  // P2: hW1 MFMA, wave = (mt = w&3 rows, nh = w>>2 col-pair), A from global.
  int mt = w & 3, nh = w >> 2;
  int colA = nh * 32 + r15, colB = colA + 16;
  const uint16_t* bptr = &W1T[((long)c * 128 + colA) * 256 + kg * 8];
  const uint16_t* arow = &EMB[((long)b * 256 + list_s[mt * 16 + r15]) * 256 + kg * 8];
  f32x4 acc0 = (f32x4){0.f, 0.f, 0.f, 0.f};
  f32x4 acc1 = (f32x4){0.f, 0.f, 0.f, 0.f};
  if (mt * 16 < n) {
    #pragma unroll
    for (int ks = 0; ks < 8; ++ks) {
      bf16x8 b0 = *(const bf16x8*)(bptr + ks * 32);
      bf16x8 b1f = *(const bf16x8*)(bptr + 16 * 256 + ks * 32);
      bf16x8 afr = *(const bf16x8*)(arow + ks * 32);
      acc0 = __builtin_amdgcn_mfma_f32_16x16x32_bf16(afr, b0, acc0, 0, 0, 0);
      acc1 = __builtin_amdgcn_mfma_f32_16x16x32_bf16(afr, b1f, acc1, 0, 0, 0);
    }
  }
  // P3: write hwt (transposed bf16); pd/ps fragment dots -> e2d_s/e2s_s temp
  {
    uint2 pA, pB;
    pA.x = (uint32_t)f2bf(acc0[0]) | ((uint32_t)f2bf(acc0[1]) << 16);
    pA.y = (uint32_t)f2bf(acc0[2]) | ((uint32_t)f2bf(acc0[3]) << 16);
    pB.x = (uint32_t)f2bf(acc1[0]) | ((uint32_t)f2bf(acc1[1]) << 16);
    pB.y = (uint32_t)f2bf(acc1[2]) | ((uint32_t)f2bf(acc1[3]) << 16);
    *(uint2*)&hwt_s[colA * 72 + mt * 16 + kg * 4] = pA;
    *(uint2*)&hwt_s[colB * 72 + mt * 16 + kg * 4] = pB;
    float adA = a1d_s[colA], adB = a1d_s[colB];
    float asA = a1s_s[colA], asB = a1s_s[colB];
    #pragma unroll
    for (int j = 0; j < 4; ++j) {
      float pd = acc0[j] * adA + acc1[j] * adB;
      float ps = acc0[j] * asA + acc1[j] * asB;
      pd += __shfl_xor(pd, 1); pd += __shfl_xor(pd, 2);
      pd += __shfl_xor(pd, 4); pd += __shfl_xor(pd, 8);
      ps += __shfl_xor(ps, 1); ps += __shfl_xor(ps, 2);
      ps += __shfl_xor(ps, 4); ps += __shfl_xor(ps, 8);
      if (r15 == 0) {
        int jm = mt * 16 + kg * 4 + j;
        e2d_s[nh * 64 + jm] = pd;   // temp pd partial
        e2s_s[nh * 64 + jm] = ps;   // temp ps partial
      }
    }
  }
  __syncthreads();  // B1
  // P4: zero alpha region; combine e1d/e1s for members
  for (int idx = tid; idx < 4608; idx += 1024)
    *(uint2*)&alpha_s[idx * 4] = (uint2){0u, 0u};
  if (tid < 64 && tid < n) {
    float sd = e2d_s[tid] + e2d_s[tid + 64] + e2d_s[tid + 128] + e2d_s[tid + 192];
    float ss = e2s_s[tid] + e2s_s[tid + 64] + e2s_s[tid + 128] + e2s_s[tid + 192];
    int rr = list_s[tid];
    e1d_s[rr] = sd;
    e1s_s[rr] = ss;
  }
  __syncthreads();  // B2
  // P5: alpha scatter + den1 (register-resident neighbor chunk)
  {
    float e1dv = e1d_s[r];
    float den = 0.f;
    #define NB_CHUNK(WORD, BASE)                                            \
      _Pragma("unroll")                                                     \
      for (int ii = 0; ii < 4; ++ii) {                                      \
        if (BASE + ii < ncnt) {                                             \
          int j = (int)((WORD >> (ii * 8)) & 255u);                         \
          float e = e1dv + e1s_s[j];                                        \
          e = fmaxf(e, 0.2f * e);                                           \
          e = fminf(e, 60.f);                                               \
          float wv = __expf(e);                                             \
          den += wv;                                                        \
          int mi = midx_g[c * 256 + j];                                     \
          if (mi >= 0) alpha_s[r * 72 + mi] = f2bf(wv);                     \
        }                                                                   \
      }
    NB_CHUNK(nbw0, 0) NB_CHUNK(nbw1, 4) NB_CHUNK(nbw2, 8) NB_CHUNK(nbw3, 12)
    #undef NB_CHUNK
    den += __shfl_xor(den, 1);
    den += __shfl_xor(den, 2);
    if (q == 0) rd1_s[r] = 1.0f / den;
  }
  __syncthreads();  // B3
  // P6: G = alpha @ hwt via MFMA. wave w -> rules w*16..+15, 8 n-tiles.
  f32x4 g[8];
  #pragma unroll
  for (int nt = 0; nt < 8; ++nt) g[nt] = (f32x4){0.f, 0.f, 0.f, 0.f};
  int kslices = (n > 32) ? 2 : 1;
  for (int ks = 0; ks < kslices; ++ks) {
    bf16x8 afr = *(const bf16x8*)&alpha_s[(w * 16 + r15) * 72 + ks * 32 + kg * 8];
    #pragma unroll
    for (int nt = 0; nt < 8; ++nt) {
      bf16x8 bfr = *(const bf16x8*)&hwt_s[(nt * 16 + r15) * 72 + ks * 32 + kg * 8];
      g[nt] = __builtin_amdgcn_mfma_f32_16x16x32_bf16(afr, bfr, g[nt], 0, 0, 0);
    }
  }
  // P7: epilogue: g = relu(G*rd1 + b1); e2 dots
  {
    float rd1v[4];
    #pragma unroll
    for (int j = 0; j < 4; ++j) rd1v[j] = rd1_s[w * 16 + kg * 4 + j];
    float ed[4] = {0.f, 0.f, 0.f, 0.f}, es[4] = {0.f, 0.f, 0.f, 0.f};
    #pragma unroll
    for (int nt = 0; nt < 8; ++nt) {
      float uf = ud2_s[nt * 16 + r15], sf = us2_s[nt * 16 + r15];
      float bf = b1_s[nt * 16 + r15];
      #pragma unroll
      for (int j = 0; j < 4; ++j) {
        float gv = fmaxf(g[nt][j] * rd1v[j] + bf, 0.f);
        g[nt][j] = gv;
        ed[j] += gv * uf;
        es[j] += gv * sf;
      }
    }
    __syncthreads();  // B4 (rd1 reads done; e2d/e2s temps dead -> real e2)
    #pragma unroll
    for (int j = 0; j < 4; ++j) {
      ed[j] += __shfl_xor(ed[j], 1); ed[j] += __shfl_xor(ed[j], 2);
      ed[j] += __shfl_xor(ed[j], 4); ed[j] += __shfl_xor(ed[j], 8);
      es[j] += __shfl_xor(es[j], 1); es[j] += __shfl_xor(es[j], 2);
      es[j] += __shfl_xor(es[j], 4); es[j] += __shfl_xor(es[j], 8);
      if (r15 == 0) {
        e2d_s[w * 16 + kg * 4 + j] = ed[j];
        e2s_s[w * 16 + kg * 4 + j] = es[j];
      }
    }
  }
  __syncthreads();  // B5
  // P8: den2 (register neighbor chunk)
  {
    float e2dv = e2d_s[r];
    float den2 = 0.f;
    #define NB_CHUNK(WORD, BASE)                                            \
      _Pragma("unroll")                                                     \
      for (int ii = 0; ii < 4; ++ii) {                                      \
        if (BASE + ii < ncnt) {                                             \
          int j = (int)((WORD >> (ii * 8)) & 255u);                         \
          float e = e2dv + e2s_s[j];                                        \
          e = fmaxf(e, 0.2f * e);                                           \
          e = fminf(e, 60.f);                                               \
          den2 += __expf(e);                                                \
        }                                                                   \
      }
    NB_CHUNK(nbw0, 0) NB_CHUNK(nbw1, 4) NB_CHUNK(nbw2, 8) NB_CHUNK(nbw3, 12)
    #undef NB_CHUNK
    den2 += __shfl_xor(den2, 1);
    den2 += __shfl_xor(den2, 2);
    if (q == 0) rd2_s[r] = 1.0f / den2;
  }
  __syncthreads();  // B6
  // P9: column weights wj[r] = sum_i alpha2[i,r]
  {
    float e2sv = e2s_s[r];
    float wj = 0.f;
    #define NB_CHUNK(WORD, BASE)                                            \
      _Pragma("unroll")                                                     \
      for (int ii = 0; ii < 4; ++ii) {                                      \
        if (BASE + ii < ncnt) {                                             \
          int i2 = (int)((WORD >> (ii * 8)) & 255u);                        \
          float e = e2d_s[i2] + e2sv;                                       \
          e = fmaxf(e, 0.2f * e);                                           \
          e = fminf(e, 60.f);                                               \
          wj += __expf(e) * rd2_s[i2];                                      \
        }                                                                   \
      }
    NB_CHUNK(nbw0, 0) NB_CHUNK(nbw1, 4) NB_CHUNK(nbw2, 8) NB_CHUNK(nbw3, 12)
    #undef NB_CHUNK
    wj += __shfl_xor(wj, 1);
    wj += __shfl_xor(wj, 2);
    if (q == 0) wj_s[r] = wj;
  }
  __syncthreads();  // B7
  // P10: t partials from live fragments (tpart aliases alpha, dead now)
  {
    float wjv[4];
    #pragma unroll
    for (int j = 0; j < 4; ++j) wjv[j] = wj_s[w * 16 + kg * 4 + j];
    #pragma unroll
    for (int nt = 0; nt < 8; ++nt) {
      float tp = wjv[0] * g[nt][0] + wjv[1] * g[nt][1] + wjv[2] * g[nt][2] + wjv[3] * g[nt][3];
      tp += __shfl_xor(tp, 16);
      tp += __shfl_xor(tp, 32);
      if (kg == 0) tpart[w][nt * 16 + r15] = tp;
    }
  }
  __syncthreads();  // B8
  // P11: t combine
  if (tid < 128) {
    float s = 0.f;
    #pragma unroll
    for (int w2 = 0; w2 < 16; ++w2) s += tpart[w2][tid];
    t_s[tid] = s;
  }
  __syncthreads();  // B9
  // P12: svec partials: all 1024 threads, coalesced W2 reads.
  {
    int col = tid & 63, fg = tid >> 6;
    float sp = 0.f;
    #pragma unroll
    for (int i = 0; i < 8; ++i) {
      int f = fg * 8 + i;
      sp += t_s[f] * W2[((long)c * 128 + f) * 64 + col];
    }
    tpart[fg][col] = sp;
  }
  __syncthreads();  // B10
  if (tid < 64) {
    float s = 256.0f * b2[c * 64 + tid];
    #pragma unroll
    for (int fg = 0; fg < 16; ++fg) s += tpart[fg][tid];
    svec[tid] = s;
  }
  __syncthreads();  // B11
  if (tid < 6) {
    float lg = 256.0f * bl[c * 6 + tid];
    for (int f = 0; f < 64; ++f) lg += svec[f] * Wl[((long)c * 64 + f) * 6 + tid];
    lvec[tid] = lg;
  }
  __syncthreads();  // B12
  if (tid == 0) {
    float mm = lvec[0];
    for (int k2 = 1; k2 < 6; ++k2) mm = fmaxf(mm, lvec[k2]);
    float ss = 0.f;
    for (int k2 = 0; k2 < 6; ++k2) ss += __expf(lvec[k2] - mm);
    float lse = mm + __logf(ss);
    for (int k2 = 0; k2 < 6; ++k2) out[((long)c * 256 + b) * 6 + k2] = lvec[k2] - lse;
  }
}

// ---------------------------------------------------------------------------
extern "C" void kernel_launch(void* const* d_in, const int* in_sizes, int n_in,
                              void* d_out, int out_size, void* d_ws, size_t ws_size,
                              hipStream_t stream)
{
  const float* vis   = (const float*)d_in[0];
  const float* basic = (const float*)d_in[1];
  const float* cruc  = (const float*)d_in[2];
  const float* Wtb   = (const float*)d_in[3];
  const float* btb   = (const float*)d_in[4];
  const float* Wtk   = (const float*)d_in[5];
  const float* btk   = (const float*)d_in[6];
  const float* Wq    = (const float*)d_in[7];
  const float* bq    = (const float*)d_in[8];
  const float* Wk    = (const float*)d_in[9];
  const float* bk    = (const float*)d_in[10];
  const float* Wv    = (const float*)d_in[11];
  const float* bv    = (const float*)d_in[12];
  const float* Wo    = (const float*)d_in[13];
  const float* bo    = (const float*)d_in[14];
  const float* W1    = (const float*)d_in[15];
  const float* a1s   = (const float*)d_in[16];
  const float* a1d   = (const float*)d_in[17];
  const float* b1    = (const float*)d_in[18];
  const float* W2    = (const float*)d_in[19];
  const float* a2s   = (const float*)d_in[20];
  const float* a2d   = (const float*)d_in[21];
  const float* b2    = (const float*)d_in[22];
  const float* Wl    = (const float*)d_in[23];
  const float* bl    = (const float*)d_in[24];
  const void*  adj   = d_in[25];
  const int*   mask  = (const int*)d_in[26];
  float* out = (float*)d_out;
  char* ws = (char*)d_ws;

  uint16_t* QBF  = (uint16_t*)(ws + 0);         // 131072
  uint32_t* ADJ  = (uint32_t*)(ws + 262144);    // 8192
  int*      CLS  = (int*)(ws + 270336);         // 1024
  int*      LST  = (int*)(ws + 271360);         // 2560
  int*      CNT  = (int*)(ws + 273920);         // 64
  int*      DEG  = (int*)(ws + 273984);         // 1024
  uint8_t*  NBR  = (uint8_t*)(ws + 275008);     // 16384
  int8_t*   MIDX = (int8_t*)(ws + 291392);      // 2560
  float*    UD2  = (float*)(ws + 293952);       // 5120
  float*    US2  = (float*)(ws + 299072);       // 5120
  uint16_t* WOT  = (uint16_t*)(ws + 304192);    // 131072
  uint16_t* WKVT = (uint16_t*)(ws + 435264);    // 262144
  uint16_t* W1T  = (uint16_t*)(ws + 697408);    // 655360
  uint16_t* KX   = (uint16_t*)(ws + 1352768);   // 8388608
  uint16_t* VX   = (uint16_t*)(ws + 9741376);   // 8388608
  uint16_t* EMB  = (uint16_t*)(ws + 18129984);  // 33554432 -> total ~49.3 MiB

  hipLaunchKernelGGL(k_front, dim3(2443), dim3(256), 0, stream,
                     adj, mask, W2, a2s, a2d, ADJ, CLS, LST, CNT, DEG, NBR, MIDX,
                     UD2, US2,
                     Wo, Wk, Wv, W1, WOT, WKVT, W1T,
                     basic, cruc, Wtb, btb, Wtk, btk, Wq, bq, QBF,
                     vis, bk, bv, KX, VX);
  hipLaunchKernelGGL(k_attn, dim3(512), dim3(512), 0, stream, QBF, KX, VX, EMB);
  hipLaunchKernelGGL(k_wo, dim3(1024), dim3(256), 0, stream, EMB, WOT, bo);
  hipLaunchKernelGGL(k_gat, dim3(2560), dim3(1024), 0, stream,
                     EMB, W1T, a1d, a1s, LST, CNT, DEG, NBR, MIDX,
                     b1, UD2, US2, W2, b2, Wl, bl, out);
}

// Round 12
// 360.972 us; speedup vs baseline: 1.1566x; 1.1566x over previous
//
#include <hip/hip_runtime.h>
#include <stdint.h>

// Sizes (fixed by the problem)
#define NB 256
#define NS 64
#define NR 256
#define NV 2000
#define NC 10
#define NK 6
#define ND 256

typedef __attribute__((ext_vector_type(8))) short bf16x8;
typedef __attribute__((ext_vector_type(4))) float f32x4;

__device__ __forceinline__ float bf2f(uint16_t u) {
  return __uint_as_float(((uint32_t)u) << 16);
}
__device__ __forceinline__ uint16_t f2bf(float f) {
  uint32_t x = __float_as_uint(f);
  x += 0x7FFFu + ((x >> 16) & 1u);
  return (uint16_t)(x >> 16);
}

// ---------------------------------------------------------------------------
// k_front: merged independent preprocessing.
//   blocks 0..10    : k_prep  (adjacency/bitmask/lists/midx + ud2/us2)
//   blocks 11..138  : k_prept (weight transposes to bf16 N-major)
//   blocks 139..394 : k_ruleq (rule embeddings + Q proj, bf16*0.125)
//   blocks 395..2442: k_kvproj (KX/VX = vis @ Wk/Wv + bias, MFMA)
// ---------------------------------------------------------------------------
__global__ __launch_bounds__(256) void k_front(
    const void* __restrict__ adj_raw, const int* __restrict__ mask,
    const float* __restrict__ W2, const float* __restrict__ a2s,
    const float* __restrict__ a2d,
    uint32_t* __restrict__ adjbits, int* __restrict__ cls,
    int* __restrict__ lists, int* __restrict__ cnt,
    int* __restrict__ deg, uint8_t* __restrict__ nbr,
    int8_t* __restrict__ midx,
    float* __restrict__ ud2, float* __restrict__ us2,
    const float* __restrict__ Wo, const float* __restrict__ Wk,
    const float* __restrict__ Wv, const float* __restrict__ W1,
    uint16_t* __restrict__ WOT, uint16_t* __restrict__ WKVT,
    uint16_t* __restrict__ W1T,
    const float* __restrict__ basic, const float* __restrict__ cruc,
    const float* __restrict__ Wtb, const float* __restrict__ btb,
    const float* __restrict__ Wtk, const float* __restrict__ btk,
    const float* __restrict__ Wq, const float* __restrict__ bq,
    uint16_t* __restrict__ Qbf,
    const float* __restrict__ vis, const float* __restrict__ bk,
    const float* __restrict__ bv,
    uint16_t* __restrict__ KX, uint16_t* __restrict__ VX)
{
  __shared__ char smem[33792];
  int bid = blockIdx.x;
  int tid = threadIdx.x;
  if (bid < 11) {
    // ---- k_prep ----
    if (bid == 0) {
      int* s_is4 = (int*)smem;
      if (tid == 0) *s_is4 = 1;
      __syncthreads();
      const uint32_t* u = (const uint32_t*)adj_raw;
      int ok = 1;
      for (int idx = tid; idx < 16384; idx += 256) {
        uint32_t v = u[idx];
        if (!(v == 0u || v == 1u || v == 0x3F800000u)) ok = 0;
      }
      if (!ok) atomicAnd(s_is4, 0);
      __syncthreads();
      int is4 = *s_is4;
      const uint8_t* b8 = (const uint8_t*)adj_raw;
      int dg = 0;
      for (int w = 0; w < 8; ++w) {
        uint32_t word = 0;
        for (int jb = 0; jb < 32; ++jb) {
          int j = w * 32 + jb;
          int bit = is4 ? (u[tid * 256 + j] != 0u) : (b8[tid * 256 + j] != 0);
          if (bit) {
            word |= (1u << jb);
            if (dg < 64) nbr[tid * 64 + dg] = (uint8_t)j;
            dg++;
          }
        }
        adjbits[tid * 8 + w] = word;
      }
      deg[tid] = (dg > 64) ? 64 : dg;
      int c = 0;
      for (int cc = 0; cc < NC; ++cc) if (mask[cc * 256 + tid] != 0) c = cc;
      cls[tid] = c;
      __syncthreads();
      if (tid == 0) {
        int cn[NC];
        for (int i = 0; i < NC; ++i) cn[i] = 0;
        for (int r = 0; r < 256; ++r) {
          int cc = cls[r];
          if (cn[cc] < 64) lists[cc * 64 + cn[cc]] = r;
          cn[cc]++;
        }
        for (int i = 0; i < NC; ++i) cnt[i] = (cn[i] > 64) ? 64 : cn[i];
        for (int i = 0; i < NC * 256; ++i) midx[i] = -1;
        for (int cc = 0; cc < NC; ++cc)
          for (int i = 0; i < cnt[cc]; ++i)
            midx[cc * 256 + lists[cc * 64 + i]] = (int8_t)i;
      }
    } else {
      int c = bid - 1;
      if (tid < 128) {
        float s1 = 0.f, s2 = 0.f;
        for (int g = 0; g < 64; ++g) {
          float w = W2[(c * 128 + tid) * 64 + g];
          s1 += w * a2d[c * 64 + g];
          s2 += w * a2s[c * 64 + g];
        }
        ud2[c * 128 + tid] = s1;
        us2[c * 128 + tid] = s2;
      }
    }
  } else if (bid < 139) {
    // ---- k_prept ----
    float (*ts)[65] = (float(*)[65])smem;
    int pb = bid - 11;
    const float* src;
    uint16_t* dst;
    int ncols, kt, nt;
    if (pb < 16)      { src = Wo; dst = WOT; ncols = 256; kt = pb >> 2; nt = pb & 3; }
    else if (pb < 32) { int t = pb - 16; src = Wk; dst = WKVT; ncols = 256; kt = t >> 2; nt = t & 3; }
    else if (pb < 48) { int t = pb - 32; src = Wv; dst = WKVT + 256 * 256; ncols = 256; kt = t >> 2; nt = t & 3; }
    else { int t = pb - 48; int c = t >> 3; int tt = t & 7;
           src = W1 + (long)c * 256 * 128; dst = W1T + (long)c * 128 * 256;
           ncols = 128; kt = tt >> 1; nt = tt & 1; }
    for (int idx = tid; idx < 4096; idx += 256) {
      int i = idx >> 6, j = idx & 63;
      ts[i][j] = src[(long)(kt * 64 + i) * ncols + nt * 64 + j];
    }
    __syncthreads();
    for (int idx = tid; idx < 4096; idx += 256) {
      int i = idx >> 6, j = idx & 63;
      dst[(long)(nt * 64 + i) * 256 + kt * 64 + j] = f2bf(ts[j][i]);
    }
  } else if (bid < 395) {
    // ---- k_ruleq ----
    float* row_s  = (float*)smem;              // 2048 f
    float* rule_s = row_s + 2048;              // 256 f
    int*   nzi    = (int*)(rule_s + 256);      // 128 i
    float* nzv    = (float*)(nzi + 128);       // 128 f
    int*   nzcp   = (int*)(nzv + 128);         // 1 i
    int r = bid - 139;
    float acc = btb[tid] + btk[tid];
    for (int m = 0; m < 2; ++m) {
      const float* src = m ? cruc : basic;
      const float* W   = m ? Wtk : Wtb;
      for (int idx = tid; idx < 2048; idx += 256)
        row_s[idx] = (idx < NV) ? src[r * NV + idx] : 0.0f;
      if (tid == 0) *nzcp = 0;
      __syncthreads();
      if (tid < 64) {
        int base = 0;
        for (int ch = 0; ch < 32; ++ch) {
          int idx = ch * 64 + tid;
          float v = row_s[idx];
          unsigned long long bm = __ballot(v != 0.0f);
          if (v != 0.0f) {
            int pos = base + (int)__popcll(bm & ((1ull << tid) - 1ull));
            if (pos < 128) { nzi[pos] = idx; nzv[pos] = v; }
          }
          base += (int)__popcll(bm);
        }
        if (tid == 0) *nzcp = (base > 128) ? 128 : base;
      }
      __syncthreads();
      int n = *nzcp;
      for (int t = 0; t < n; ++t) acc += nzv[t] * W[nzi[t] * 256 + tid];
      __syncthreads();
    }
    rule_s[tid] = acc;
    __syncthreads();
    float q = bq[tid];
    for (int k2 = 0; k2 < 256; ++k2) q += rule_s[k2] * Wq[k2 * 256 + tid];
    Qbf[r * 256 + tid] = f2bf(q * 0.125f);
  } else {
    // ---- k_kvproj ----
    uint16_t* A_s = (uint16_t*)smem;  // 64 x 264
    int t = bid - 395;
    int bx = t & 255, by = t >> 8;
    int lane = tid & 63, w = tid >> 6;
    int r15 = lane & 15, kg = lane >> 4;
    long m0 = (long)bx * 64;
    int n0 = by * 64 + w * 16;
    for (int idx = tid; idx < 2048; idx += 256) {
      int r = idx >> 5, ch = idx & 31;
      const float4* p = (const float4*)&vis[(m0 + r) * 256 + ch * 8];
      float4 v0 = p[0], v1 = p[1];
      uint4 wd;
      wd.x = (uint32_t)f2bf(v0.x) | ((uint32_t)f2bf(v0.y) << 16);
      wd.y = (uint32_t)f2bf(v0.z) | ((uint32_t)f2bf(v0.w) << 16);
      wd.z = (uint32_t)f2bf(v1.x) | ((uint32_t)f2bf(v1.y) << 16);
      wd.w = (uint32_t)f2bf(v1.z) | ((uint32_t)f2bf(v1.w) << 16);
      *(uint4*)&A_s[r * 264 + ch * 8] = wd;
    }
    __syncthreads();
    const uint16_t* bptr = &WKVT[(long)(n0 + r15) * 256 + kg * 8];
    f32x4 acc[4];
    #pragma unroll
    for (int mt = 0; mt < 4; ++mt) acc[mt] = (f32x4){0.f, 0.f, 0.f, 0.f};
    #pragma unroll
    for (int ks = 0; ks < 8; ++ks) {
      bf16x8 bfr = *(const bf16x8*)(bptr + ks * 32);
      #pragma unroll
      for (int mt = 0; mt < 4; ++mt) {
        bf16x8 afr = *(const bf16x8*)&A_s[(mt * 16 + r15) * 264 + kg * 8 + ks * 32];
        acc[mt] = __builtin_amdgcn_mfma_f32_16x16x32_bf16(afr, bfr, acc[mt], 0, 0, 0);
      }
    }
    int col = n0 + r15;
    float bb = (col < 256) ? bk[col] : bv[col - 256];
    uint16_t* outp = (col < 256) ? KX : VX;
    int oc = (col < 256) ? col : col - 256;
    #pragma unroll
    for (int mt = 0; mt < 4; ++mt)
      #pragma unroll
      for (int j = 0; j < 4; ++j) {
        long row = m0 + mt * 16 + kg * 4 + j;
        outp[row * 256 + oc] = f2bf(acc[mt][j] + bb);
      }
  }
}

// ---------------------------------------------------------------------------
// k_attn (MFMA): block = (batch b, half of rules), 512 thr / 8 waves.
// ---------------------------------------------------------------------------
__global__ __launch_bounds__(512) void k_attn(const uint16_t* __restrict__ Qbf,
                         const uint16_t* __restrict__ KX, const uint16_t* __restrict__ VX,
                         uint16_t* __restrict__ EMB)
{
  __shared__ uint16_t p_s[128 * 72];
  __shared__ uint16_t vt_s[64 * 72];
  int tid = threadIdx.x;
  int lane = tid & 63, w = tid >> 6;   // 8 waves
  int r15 = lane & 15, kg = lane >> 4;
  int b = blockIdx.x >> 1;
  int rbase = (blockIdx.x & 1) * 128;
  for (int h = 0; h < 4; ++h) {
    __syncthreads();  // prev head's vt_s reads done
    for (int idx = tid; idx < 2048; idx += 512) {
      int s = idx >> 5, d2 = (idx & 31) * 2;
      uint32_t v = *(const uint32_t*)&VX[((long)(b * 64 + s)) * 256 + h * 64 + d2];
      vt_s[d2 * 72 + s] = (uint16_t)(v & 0xffff);
      vt_s[(d2 + 1) * 72 + s] = (uint16_t)(v >> 16);
    }
    __syncthreads();
    f32x4 sacc[4];
    #pragma unroll
    for (int nt = 0; nt < 4; ++nt) sacc[nt] = (f32x4){0.f, 0.f, 0.f, 0.f};
    #pragma unroll
    for (int ks = 0; ks < 2; ++ks) {
      bf16x8 afr = *(const bf16x8*)&Qbf[(long)(rbase + w * 16 + r15) * 256 + h * 64 + ks * 32 + kg * 8];
      #pragma unroll
      for (int nt = 0; nt < 4; ++nt) {
        bf16x8 bfr = *(const bf16x8*)&KX[((long)(b * 64 + nt * 16 + r15)) * 256 + h * 64 + ks * 32 + kg * 8];
        sacc[nt] = __builtin_amdgcn_mfma_f32_16x16x32_bf16(afr, bfr, sacc[nt], 0, 0, 0);
      }
    }
    #pragma unroll
    for (int j = 0; j < 4; ++j) {
      float m = sacc[0][j];
      #pragma unroll
      for (int nt = 1; nt < 4; ++nt) m = fmaxf(m, sacc[nt][j]);
      m = fmaxf(m, __shfl_xor(m, 1));
      m = fmaxf(m, __shfl_xor(m, 2));
      m = fmaxf(m, __shfl_xor(m, 4));
      m = fmaxf(m, __shfl_xor(m, 8));
      float pv[4];
      float sum = 0.f;
      #pragma unroll
      for (int nt = 0; nt < 4; ++nt) { pv[nt] = __expf(sacc[nt][j] - m); sum += pv[nt]; }
      sum += __shfl_xor(sum, 1);
      sum += __shfl_xor(sum, 2);
      sum += __shfl_xor(sum, 4);
      sum += __shfl_xor(sum, 8);
      float rs = 1.0f / sum;
      #pragma unroll
      for (int nt = 0; nt < 4; ++nt)
        p_s[(w * 16 + kg * 4 + j) * 72 + nt * 16 + r15] = f2bf(pv[nt] * rs);
    }
    f32x4 oacc[4];
    #pragma unroll
    for (int nt = 0; nt < 4; ++nt) oacc[nt] = (f32x4){0.f, 0.f, 0.f, 0.f};
    #pragma unroll
    for (int ks = 0; ks < 2; ++ks) {
      bf16x8 afr = *(const bf16x8*)&p_s[(w * 16 + r15) * 72 + ks * 32 + kg * 8];
      #pragma unroll
      for (int nt = 0; nt < 4; ++nt) {
        bf16x8 bfr = *(const bf16x8*)&vt_s[(nt * 16 + r15) * 72 + ks * 32 + kg * 8];
        oacc[nt] = __builtin_amdgcn_mfma_f32_16x16x32_bf16(afr, bfr, oacc[nt], 0, 0, 0);
      }
    }
    #pragma unroll
    for (int nt = 0; nt < 4; ++nt)
      #pragma unroll
      for (int j = 0; j < 4; ++j) {
        long row = (long)(b * 256 + rbase + w * 16 + kg * 4 + j);
        EMB[row * 256 + h * 64 + nt * 16 + r15] = f2bf(oacc[nt][j]);
      }
  }
}

// ---------------------------------------------------------------------------
// k_wo (MFMA): EMB = EMB @ Wo + bo, in place (race-free per 64-row block).
// ---------------------------------------------------------------------------
__global__ __launch_bounds__(256) void k_wo(uint16_t* __restrict__ EMB,
                    const uint16_t* __restrict__ WOT, const float* __restrict__ bo)
{
  __shared__ uint16_t A_s[64 * 264];
  int tid = threadIdx.x;
  int lane = tid & 63, w = tid >> 6;
  int r15 = lane & 15, kg = lane >> 4;
  long m0 = (long)blockIdx.x * 64;
  for (int idx = tid; idx < 2048; idx += 256) {
    int r = idx >> 5, ch = idx & 31;
    uint4 v = *(const uint4*)&EMB[(m0 + r) * 256 + ch * 8];
    *(uint4*)&A_s[r * 264 + ch * 8] = v;
  }
  __syncthreads();
  #pragma unroll
  for (int nt = 0; nt < 4; ++nt) {
    int n0 = nt * 64 + w * 16;
    const uint16_t* bptr = &WOT[(long)(n0 + r15) * 256 + kg * 8];
    f32x4 acc[4];
    #pragma unroll
    for (int mt = 0; mt < 4; ++mt) acc[mt] = (f32x4){0.f, 0.f, 0.f, 0.f};
    #pragma unroll
    for (int ks = 0; ks < 8; ++ks) {
      bf16x8 bfr = *(const bf16x8*)(bptr + ks * 32);
      #pragma unroll
      for (int mt = 0; mt < 4; ++mt) {
        bf16x8 afr = *(const bf16x8*)&A_s[(mt * 16 + r15) * 264 + kg * 8 + ks * 32];
        acc[mt] = __builtin_amdgcn_mfma_f32_16x16x32_bf16(afr, bfr, acc[mt], 0, 0, 0);
      }
    }
    int col = n0 + r15;
    float bb = bo[col];
    #pragma unroll
    for (int mt = 0; mt < 4; ++mt)
      #pragma unroll
      for (int j = 0; j < 4; ++j) {
        long row = m0 + mt * 16 + kg * 4 + j;
        EMB[row * 256 + col] = f2bf(acc[mt][j] + bb);
      }
  }
}

// ---------------------------------------------------------------------------
// k_gat v5: TWO batches per block (bA, bB), grid 1280 = c*128 + bp.
// Amortizes the barrier chain, W1T b-frags, neighbor regs, midx (LDS-staged),
// class consts over 2 batches; tail phases run batches in thread halves.
// LDS ~124 KB (1 block/CU — which was already the occupancy ceiling).
// ---------------------------------------------------------------------------
__global__ __launch_bounds__(1024) void k_gat(
    const uint16_t* __restrict__ EMB, const uint16_t* __restrict__ W1T,
    const float* __restrict__ a1d, const float* __restrict__ a1s,
    const int* __restrict__ lists, const int* __restrict__ cnt_g,
    const int* __restrict__ deg_g, const uint8_t* __restrict__ nbr_g,
    const int8_t* __restrict__ midx_g,
    const float* __restrict__ b1, const float* __restrict__ ud2_g,
    const float* __restrict__ us2_g, const float* __restrict__ W2,
    const float* __restrict__ b2, const float* __restrict__ Wl,
    const float* __restrict__ bl, float* __restrict__ out)
{
  __shared__ uint16_t alphaA[256 * 72], alphaB[256 * 72]; // later: tpartA/B
  __shared__ uint16_t hwtA[128 * 72], hwtB[128 * 72];     // later: svec/lvec
  __shared__ float e1dA_s[256], e1sA_s[256], e1dB_s[256], e1sB_s[256];
  __shared__ float rd1A_s[256], rd1B_s[256];              // later: wjA/wjB
  __shared__ float e2dA_s[256], e2sA_s[256], e2dB_s[256], e2sB_s[256];
  __shared__ float rd2A_s[256], rd2B_s[256];
  __shared__ float a1d_s[128], a1s_s[128], b1_s[128], ud2_s[128], us2_s[128];
  __shared__ float t_sA[128], t_sB[128];
  __shared__ int   list_s[64];
  __shared__ int8_t midx_s[256];
  float (*tpartA)[128] = (float(*)[128])alphaA;
  float (*tpartB)[128] = (float(*)[128])alphaB;
  float* wjA_s = rd1A_s;
  float* wjB_s = rd1B_s;
  float* svecA = (float*)hwtA;
  float* lvecA = (float*)(hwtA + 256);
  float* svecB = (float*)hwtB;
  float* lvecB = (float*)(hwtB + 256);
  int tid = threadIdx.x;
  int lane = tid & 63, w = tid >> 6;
  int r15 = lane & 15, kg = lane >> 4;
  int c = blockIdx.x >> 7, bp = blockIdx.x & 127;
  int bA = bp * 2, bB = bp * 2 + 1;
  int n = cnt_g[c];
  if (tid < 64) list_s[tid] = (tid < n) ? lists[c * 64 + tid] : 0;
  if (tid >= 64 && tid < 128) {
    int i = tid - 64;
    ((uint32_t*)midx_s)[i] = ((const uint32_t*)(midx_g + (long)c * 256))[i];
  }
  if (tid < 128) {
    a1d_s[tid] = a1d[c * 128 + tid];
    a1s_s[tid] = a1s[c * 128 + tid];
    b1_s[tid]  = b1[c * 128 + tid];
    ud2_s[tid] = ud2_g[c * 128 + tid];
    us2_s[tid] = us2_g[c * 128 + tid];
  }
  if (tid < 256) {
    e1dA_s[tid] = 0.f; e1sA_s[tid] = 0.f;
    e1dB_s[tid] = 0.f; e1sB_s[tid] = 0.f;
  }
  // neighbor chunk prefetch: thread (r,q) owns neighbors [q*16, q*16+16)
  int r = tid >> 2, q = tid & 3;
  int dg = deg_g[r];
  int t0 = q * 16;
  int ncnt = dg - t0; ncnt = (ncnt < 0) ? 0 : (ncnt > 16 ? 16 : ncnt);
  const uint32_t* np = (const uint32_t*)&nbr_g[r * 64 + t0];
  uint32_t nbw0 = np[0], nbw1 = np[1], nbw2 = np[2], nbw3 = np[3];
  __syncthreads();  // B0
  // P2: hW1 MFMA for both batches; W1T b-frags shared.
  int mt = w & 3, nh = w >> 2;
  int colA = nh * 32 + r15, colB = colA + 16;
  const uint16_t* bptr = &W1T[((long)c * 128 + colA) * 256 + kg * 8];
  const uint16_t* arA = &EMB[((long)bA * 256 + list_s[mt * 16 + r15]) * 256 + kg * 8];
  const uint16_t* arB = &EMB[((long)bB * 256 + list_s[mt * 16 + r15]) * 256 + kg * 8];
  f32x4 aA0 = (f32x4){0.f,0.f,0.f,0.f}, aA1 = (f32x4){0.f,0.f,0.f,0.f};
  f32x4 aB0 = (f32x4){0.f,0.f,0.f,0.f}, aB1 = (f32x4){0.f,0.f,0.f,0.f};
  if (mt * 16 < n) {
    #pragma unroll
    for (int ks = 0; ks < 8; ++ks) {
      bf16x8 b0 = *(const bf16x8*)(bptr + ks * 32);
      bf16x8 b1f = *(const bf16x8*)(bptr + 16 * 256 + ks * 32);
      bf16x8 afA = *(const bf16x8*)(arA + ks * 32);
      bf16x8 afB = *(const bf16x8*)(arB + ks * 32);
      aA0 = __builtin_amdgcn_mfma_f32_16x16x32_bf16(afA, b0, aA0, 0, 0, 0);
      aA1 = __builtin_amdgcn_mfma_f32_16x16x32_bf16(afA, b1f, aA1, 0, 0, 0);
      aB0 = __builtin_amdgcn_mfma_f32_16x16x32_bf16(afB, b0, aB0, 0, 0, 0);
      aB1 = __builtin_amdgcn_mfma_f32_16x16x32_bf16(afB, b1f, aB1, 0, 0, 0);
    }
  }
  // P3: write hwt (transposed bf16) + pd/ps fragment dots -> e2 temps
  {
    uint2 pk;
    pk.x = (uint32_t)f2bf(aA0[0]) | ((uint32_t)f2bf(aA0[1]) << 16);
    pk.y = (uint32_t)f2bf(aA0[2]) | ((uint32_t)f2bf(aA0[3]) << 16);
    *(uint2*)&hwtA[colA * 72 + mt * 16 + kg * 4] = pk;
    pk.x = (uint32_t)f2bf(aA1[0]) | ((uint32_t)f2bf(aA1[1]) << 16);
    pk.y = (uint32_t)f2bf(aA1[2]) | ((uint32_t)f2bf(aA1[3]) << 16);
    *(uint2*)&hwtA[colB * 72 + mt * 16 + kg * 4] = pk;
    pk.x = (uint32_t)f2bf(aB0[0]) | ((uint32_t)f2bf(aB0[1]) << 16);
    pk.y = (uint32_t)f2bf(aB0[2]) | ((uint32_t)f2bf(aB0[3]) << 16);
    *(uint2*)&hwtB[colA * 72 + mt * 16 + kg * 4] = pk;
    pk.x = (uint32_t)f2bf(aB1[0]) | ((uint32_t)f2bf(aB1[1]) << 16);
    pk.y = (uint32_t)f2bf(aB1[2]) | ((uint32_t)f2bf(aB1[3]) << 16);
    *(uint2*)&hwtB[colB * 72 + mt * 16 + kg * 4] = pk;
    float adA = a1d_s[colA], adB = a1d_s[colB];
    float asA = a1s_s[colA], asB = a1s_s[colB];
    #pragma unroll
    for (int j = 0; j < 4; ++j) {
      float pdA = aA0[j] * adA + aA1[j] * adB;
      float psA = aA0[j] * asA + aA1[j] * asB;
      float pdB = aB0[j] * adA + aB1[j] * adB;
      float psB = aB0[j] * asA + aB1[j] * asB;
      pdA += __shfl_xor(pdA, 1); pdA += __shfl_xor(pdA, 2);
      pdA += __shfl_xor(pdA, 4); pdA += __shfl_xor(pdA, 8);
      psA += __shfl_xor(psA, 1); psA += __shfl_xor(psA, 2);
      psA += __shfl_xor(psA, 4); psA += __shfl_xor(psA, 8);
      pdB += __shfl_xor(pdB, 1); pdB += __shfl_xor(pdB, 2);
      pdB += __shfl_xor(pdB, 4); pdB += __shfl_xor(pdB, 8);
      psB += __shfl_xor(psB, 1); psB += __shfl_xor(psB, 2);
      psB += __shfl_xor(psB, 4); psB += __shfl_xor(psB, 8);
      if (r15 == 0) {
        int jm = mt * 16 + kg * 4 + j;
        e2dA_s[nh * 64 + jm] = pdA;
        e2sA_s[nh * 64 + jm] = psA;
        e2dB_s[nh * 64 + jm] = pdB;
        e2sB_s[nh * 64 + jm] = psB;
      }
    }
  }
  __syncthreads();  // B1
  // P4: zero own alpha row slices; combine e1d/e1s for members
  {
    uint32_t* zA = (uint32_t*)&alphaA[r * 72 + q * 18];
    uint32_t* zB = (uint32_t*)&alphaB[r * 72 + q * 18];
    #pragma unroll
    for (int i = 0; i < 9; ++i) { zA[i] = 0u; zB[i] = 0u; }
  }
  if (tid < 64 && tid < n) {
    float sdA = e2dA_s[tid] + e2dA_s[tid + 64] + e2dA_s[tid + 128] + e2dA_s[tid + 192];
    float ssA = e2sA_s[tid] + e2sA_s[tid + 64] + e2sA_s[tid + 128] + e2sA_s[tid + 192];
    float sdB = e2dB_s[tid] + e2dB_s[tid + 64] + e2dB_s[tid + 128] + e2dB_s[tid + 192];
    float ssB = e2sB_s[tid] + e2sB_s[tid + 64] + e2sB_s[tid + 128] + e2sB_s[tid + 192];
    int rr = list_s[tid];
    e1dA_s[rr] = sdA; e1sA_s[rr] = ssA;
    e1dB_s[rr] = sdB; e1sB_s[rr] = ssB;
  }
  __syncthreads();  // B2
  // P5: alpha scatter + den1 (both batches; register neighbor chunk)
  {
    float e1dAv = e1dA_s[r], e1dBv = e1dB_s[r];
    float denA = 0.f, denB = 0.f;
    #define NB_CHUNK(WORD, BASE)                                            \
      _Pragma("unroll")                                                     \
      for (int ii = 0; ii < 4; ++ii) {                                      \
        if (BASE + ii < ncnt) {                                             \
          int j = (int)((WORD >> (ii * 8)) & 255u);                         \
          float eA = e1dAv + e1sA_s[j];                                     \
          eA = fmaxf(eA, 0.2f * eA); eA = fminf(eA, 60.f);                  \
          float wA = __expf(eA); denA += wA;                                \
          float eB = e1dBv + e1sB_s[j];                                     \
          eB = fmaxf(eB, 0.2f * eB); eB = fminf(eB, 60.f);                  \
          float wB = __expf(eB); denB += wB;                                \
          int mi = midx_s[j];                                               \
          if (mi >= 0) {                                                    \
            alphaA[r * 72 + mi] = f2bf(wA);                                 \
            alphaB[r * 72 + mi] = f2bf(wB);                                 \
          }                                                                 \
        }                                                                   \
      }
    NB_CHUNK(nbw0, 0) NB_CHUNK(nbw1, 4) NB_CHUNK(nbw2, 8) NB_CHUNK(nbw3, 12)
    #undef NB_CHUNK
    denA += __shfl_xor(denA, 1); denA += __shfl_xor(denA, 2);
    denB += __shfl_xor(denB, 1); denB += __shfl_xor(denB, 2);
    if (q == 0) { rd1A_s[r] = 1.0f / denA; rd1B_s[r] = 1.0f / denB; }
  }
  __syncthreads();  // B3
  // P6: G = alpha @ hwt via MFMA, both batches. wave w -> rules w*16..+15.
  f32x4 gA[8], gB[8];
  #pragma unroll
  for (int nt = 0; nt < 8; ++nt) {
    gA[nt] = (f32x4){0.f, 0.f, 0.f, 0.f};
    gB[nt] = (f32x4){0.f, 0.f, 0.f, 0.f};
  }
  int kslices = (n > 32) ? 2 : 1;
  for (int ks = 0; ks < kslices; ++ks) {
    bf16x8 afA = *(const bf16x8*)&alphaA[(w * 16 + r15) * 72 + ks * 32 + kg * 8];
    bf16x8 afB = *(const bf16x8*)&alphaB[(w * 16 + r15) * 72 + ks * 32 + kg * 8];
    #pragma unroll
    for (int nt = 0; nt < 8; ++nt) {
      bf16x8 bfA = *(const bf16x8*)&hwtA[(nt * 16 + r15) * 72 + ks * 32 + kg * 8];
      bf16x8 bfB = *(const bf16x8*)&hwtB[(nt * 16 + r15) * 72 + ks * 32 + kg * 8];
      gA[nt] = __builtin_amdgcn_mfma_f32_16x16x32_bf16(afA, bfA, gA[nt], 0, 0, 0);
      gB[nt] = __builtin_amdgcn_mfma_f32_16x16x32_bf16(afB, bfB, gB[nt], 0, 0, 0);
    }
  }
  // P7: epilogue both batches: g = relu(G*rd1 + b1); e2 dots
  {
    float rdA[4], rdB[4];
    #pragma unroll
    for (int j = 0; j < 4; ++j) {
      rdA[j] = rd1A_s[w * 16 + kg * 4 + j];
      rdB[j] = rd1B_s[w * 16 + kg * 4 + j];
    }
    float edA[4] = {0.f,0.f,0.f,0.f}, esA[4] = {0.f,0.f,0.f,0.f};
    float edB[4] = {0.f,0.f,0.f,0.f}, esB[4] = {0.f,0.f,0.f,0.f};
    #pragma unroll
    for (int nt = 0; nt < 8; ++nt) {
      float uf = ud2_s[nt * 16 + r15], sf = us2_s[nt * 16 + r15];
      float bf = b1_s[nt * 16 + r15];
      #pragma unroll
      for (int j = 0; j < 4; ++j) {
        float gvA = fmaxf(gA[nt][j] * rdA[j] + bf, 0.f);
        gA[nt][j] = gvA;
        edA[j] += gvA * uf; esA[j] += gvA * sf;
        float gvB = fmaxf(gB[nt][j] * rdB[j] + bf, 0.f);
        gB[nt][j] = gvB;
        edB[j] += gvB * uf; esB[j] += gvB * sf;
      }
    }
    #pragma unroll
    for (int j = 0; j < 4; ++j) {
      edA[j] += __shfl_xor(edA[j], 1); edA[j] += __shfl_xor(edA[j], 2);
      edA[j] += __shfl_xor(edA[j], 4); edA[j] += __shfl_xor(edA[j], 8);
      esA[j] += __shfl_xor(esA[j], 1); esA[j] += __shfl_xor(esA[j], 2);
      esA[j] += __shfl_xor(esA[j], 4); esA[j] += __shfl_xor(esA[j], 8);
      edB[j] += __shfl_xor(edB[j], 1); edB[j] += __shfl_xor(edB[j], 2);
      edB[j] += __shfl_xor(edB[j], 4); edB[j] += __shfl_xor(edB[j], 8);
      esB[j] += __shfl_xor(esB[j], 1); esB[j] += __shfl_xor(esB[j], 2);
      esB[j] += __shfl_xor(esB[j], 4); esB[j] += __shfl_xor(esB[j], 8);
      if (r15 == 0) {
        int rr = w * 16 + kg * 4 + j;
        e2dA_s[rr] = edA[j]; e2sA_s[rr] = esA[j];
        e2dB_s[rr] = edB[j]; e2sB_s[rr] = esB[j];
      }
    }
  }
  __syncthreads();  // B4
  // P8: den2 both batches
  {
    float e2dAv = e2dA_s[r], e2dBv = e2dB_s[r];
    float dnA = 0.f, dnB = 0.f;
    #define NB_CHUNK(WORD, BASE)                                            \
      _Pragma("unroll")                                                     \
      for (int ii = 0; ii < 4; ++ii) {                                      \
        if (BASE + ii < ncnt) {                                             \
          int j = (int)((WORD >> (ii * 8)) & 255u);                         \
          float eA = e2dAv + e2sA_s[j];                                     \
          eA = fmaxf(eA, 0.2f * eA); eA = fminf(eA, 60.f);                  \
          dnA += __expf(eA);                                                \
          float eB = e2dBv + e2sB_s[j];                                     \
          eB = fmaxf(eB, 0.2f * eB); eB = fminf(eB, 60.f);                  \
          dnB += __expf(eB);                                                \
        }                                                                   \
      }
    NB_CHUNK(nbw0, 0) NB_CHUNK(nbw1, 4) NB_CHUNK(nbw2, 8) NB_CHUNK(nbw3, 12)
    #undef NB_CHUNK
    dnA += __shfl_xor(dnA, 1); dnA += __shfl_xor(dnA, 2);
    dnB += __shfl_xor(dnB, 1); dnB += __shfl_xor(dnB, 2);
    if (q == 0) { rd2A_s[r] = 1.0f / dnA; rd2B_s[r] = 1.0f / dnB; }
  }
  __syncthreads();  // B5
  // P9: column weights wj[r] = sum_i alpha2[i,r], both batches
  {
    float e2sAv = e2sA_s[r], e2sBv = e2sB_s[r];
    float wjA = 0.f, wjB = 0.f;
    #define NB_CHUNK(WORD, BASE)                                            \
      _Pragma("unroll")                                                     \
      for (int ii = 0; ii < 4; ++ii) {                                      \
        if (BASE + ii < ncnt) {                                             \
          int i2 = (int)((WORD >> (ii * 8)) & 255u);                        \
          float eA = e2dA_s[i2] + e2sAv;                                    \
          eA = fmaxf(eA, 0.2f * eA); eA = fminf(eA, 60.f);                  \
          wjA += __expf(eA) * rd2A_s[i2];                                   \
          float eB = e2dB_s[i2] + e2sBv;                                    \
          eB = fmaxf(eB, 0.2f * eB); eB = fminf(eB, 60.f);                  \
          wjB += __expf(eB) * rd2B_s[i2];                                   \
        }                                                                   \
      }
    NB_CHUNK(nbw0, 0) NB_CHUNK(nbw1, 4) NB_CHUNK(nbw2, 8) NB_CHUNK(nbw3, 12)
    #undef NB_CHUNK
    wjA += __shfl_xor(wjA, 1); wjA += __shfl_xor(wjA, 2);
    wjB += __shfl_xor(wjB, 1); wjB += __shfl_xor(wjB, 2);
    if (q == 0) { wjA_s[r] = wjA; wjB_s[r] = wjB; }
  }
  __syncthreads();  // B6
  // P10: t partials from live fragments (tpart aliases alpha, dead now)
  {
    float wvA[4], wvB[4];
    #pragma unroll
    for (int j = 0; j < 4; ++j) {
      wvA[j] = wjA_s[w * 16 + kg * 4 + j];
      wvB[j] = wjB_s[w * 16 + kg * 4 + j];
    }
    #pragma unroll
    for (int nt = 0; nt < 8; ++nt) {
      float tpA = wvA[0]*gA[nt][0] + wvA[1]*gA[nt][1] + wvA[2]*gA[nt][2] + wvA[3]*gA[nt][3];
      float tpB = wvB[0]*gB[nt][0] + wvB[1]*gB[nt][1] + wvB[2]*gB[nt][2] + wvB[3]*gB[nt][3];
      tpA += __shfl_xor(tpA, 16); tpA += __shfl_xor(tpA, 32);
      tpB += __shfl_xor(tpB, 16); tpB += __shfl_xor(tpB, 32);
      if (kg == 0) {
        tpartA[w][nt * 16 + r15] = tpA;
        tpartB[w][nt * 16 + r15] = tpB;
      }
    }
  }
  __syncthreads();  // B7
  // P11: t combine (thread halves)
  if (tid < 128) {
    float s = 0.f;
    #pragma unroll
    for (int w2 = 0; w2 < 16; ++w2) s += tpartA[w2][tid];
    t_sA[tid] = s;
  } else if (tid < 256) {
    int f = tid - 128;
    float s = 0.f;
    #pragma unroll
    for (int w2 = 0; w2 < 16; ++w2) s += tpartB[w2][f];
    t_sB[f] = s;
  }
  __syncthreads();  // B8
  // P12: svec partials: 512 threads per batch, coalesced W2 reads.
  {
    int batch = tid >> 9;
    int tt = tid & 511;
    int col = tt & 63, fg = tt >> 6;  // fg 0..7, 16 f each
    const float* tsrc = batch ? t_sB : t_sA;
    float sp = 0.f;
    #pragma unroll
    for (int i = 0; i < 16; ++i) {
      int f = fg * 16 + i;
      sp += tsrc[f] * W2[((long)c * 128 + f) * 64 + col];
    }
    if (batch) tpartB[fg][col] = sp; else tpartA[fg][col] = sp;
  }
  __syncthreads();  // B9
  if (tid < 64) {
    float s = 256.0f * b2[c * 64 + tid];
    #pragma unroll
    for (int fg = 0; fg < 8; ++fg) s += tpartA[fg][tid];
    svecA[tid] = s;
  } else if (tid >= 512 && tid < 576) {
    int col = tid - 512;
    float s = 256.0f * b2[c * 64 + col];
    #pragma unroll
    for (int fg = 0; fg < 8; ++fg) s += tpartB[fg][col];
    svecB[col] = s;
  }
  __syncthreads();  // B10
  if (tid < 6) {
    float lg = 256.0f * bl[c * 6 + tid];
    for (int f = 0; f < 64; ++f) lg += svecA[f] * Wl[((long)c * 64 + f) * 6 + tid];
    lvecA[tid] = lg;
  } else if (tid >= 512 && tid < 518) {
    int k = tid - 512;
    float lg = 256.0f * bl[c * 6 + k];
    for (int f = 0; f < 64; ++f) lg += svecB[f] * Wl[((long)c * 64 + f) * 6 + k];
    lvecB[k] = lg;
  }
  __syncthreads();  // B11
  if (tid == 0) {
    float mm = lvecA[0];
    for (int k2 = 1; k2 < 6; ++k2) mm = fmaxf(mm, lvecA[k2]);
    float ss = 0.f;
    for (int k2 = 0; k2 < 6; ++k2) ss += __expf(lvecA[k2] - mm);
    float lse = mm + __logf(ss);
    for (int k2 = 0; k2 < 6; ++k2) out[((long)c * 256 + bA) * 6 + k2] = lvecA[k2] - lse;
  } else if (tid == 512) {
    float mm = lvecB[0];
    for (int k2 = 1; k2 < 6; ++k2) mm = fmaxf(mm, lvecB[k2]);
    float ss = 0.f;
    for (int k2 = 0; k2 < 6; ++k2) ss += __expf(lvecB[k2] - mm);
    float lse = mm + __logf(ss);
    for (int k2 = 0; k2 < 6; ++k2) out[((long)c * 256 + bB) * 6 + k2] = lvecB[k2] - lse;
  }
}

// ---------------------------------------------------------------------------
extern "C" void kernel_launch(void* const* d_in, const int* in_sizes, int n_in,
                              void* d_out, int out_size, void* d_ws, size_t ws_size,
                              hipStream_t stream)
{
  const float* vis   = (const float*)d_in[0];
  const float* basic = (const float*)d_in[1];
  const float* cruc  = (const float*)d_in[2];
  const float* Wtb   = (const float*)d_in[3];
  const float* btb   = (const float*)d_in[4];
  const float* Wtk   = (const float*)d_in[5];
  const float* btk   = (const float*)d_in[6];
  const float* Wq    = (const float*)d_in[7];
  const float* bq    = (const float*)d_in[8];
  const float* Wk    = (const float*)d_in[9];
  const float* bk    = (const float*)d_in[10];
  const float* Wv    = (const float*)d_in[11];
  const float* bv    = (const float*)d_in[12];
  const float* Wo    = (const float*)d_in[13];
  const float* bo    = (const float*)d_in[14];
  const float* W1    = (const float*)d_in[15];
  const float* a1s   = (const float*)d_in[16];
  const float* a1d   = (const float*)d_in[17];
  const float* b1    = (const float*)d_in[18];
  const float* W2    = (const float*)d_in[19];
  const float* a2s   = (const float*)d_in[20];
  const float* a2d   = (const float*)d_in[21];
  const float* b2    = (const float*)d_in[22];
  const float* Wl    = (const float*)d_in[23];
  const float* bl    = (const float*)d_in[24];
  const void*  adj   = d_in[25];
  const int*   mask  = (const int*)d_in[26];
  float* out = (float*)d_out;
  char* ws = (char*)d_ws;

  uint16_t* QBF  = (uint16_t*)(ws + 0);         // 131072
  uint32_t* ADJ  = (uint32_t*)(ws + 262144);    // 8192
  int*      CLS  = (int*)(ws + 270336);         // 1024
  int*      LST  = (int*)(ws + 271360);         // 2560
  int*      CNT  = (int*)(ws + 273920);         // 64
  int*      DEG  = (int*)(ws + 273984);         // 1024
  uint8_t*  NBR  = (uint8_t*)(ws + 275008);     // 16384
  int8_t*   MIDX = (int8_t*)(ws + 291392);      // 2560
  float*    UD2  = (float*)(ws + 293952);       // 5120
  float*    US2  = (float*)(ws + 299072);       // 5120
  uint16_t* WOT  = (uint16_t*)(ws + 304192);    // 131072
  uint16_t* WKVT = (uint16_t*)(ws + 435264);    // 262144
  uint16_t* W1T  = (uint16_t*)(ws + 697408);    // 655360
  uint16_t* KX   = (uint16_t*)(ws + 1352768);   // 8388608
  uint16_t* VX   = (uint16_t*)(ws + 9741376);   // 8388608
  uint16_t* EMB  = (uint16_t*)(ws + 18129984);  // 33554432 -> total ~49.3 MiB

  hipLaunchKernelGGL(k_front, dim3(2443), dim3(256), 0, stream,
                     adj, mask, W2, a2s, a2d, ADJ, CLS, LST, CNT, DEG, NBR, MIDX,
                     UD2, US2,
                     Wo, Wk, Wv, W1, WOT, WKVT, W1T,
                     basic, cruc, Wtb, btb, Wtk, btk, Wq, bq, QBF,
                     vis, bk, bv, KX, VX);
  hipLaunchKernelGGL(k_attn, dim3(512), dim3(512), 0, stream, QBF, KX, VX, EMB);
  hipLaunchKernelGGL(k_wo, dim3(1024), dim3(256), 0, stream, EMB, WOT, bo);
  hipLaunchKernelGGL(k_gat, dim3(1280), dim3(1024), 0, stream,
                     EMB, W1T, a1d, a1s, LST, CNT, DEG, NBR, MIDX,
                     b1, UD2, US2, W2, b2, Wl, bl, out);
}

// Round 13
// 338.450 us; speedup vs baseline: 1.2336x; 1.0665x over previous
//
#include <hip/hip_runtime.h>
#include <stdint.h>

// Sizes (fixed by the problem)
#define NB 256
#define NS 64
#define NR 256
#define NV 2000
#define NC 10
#define NK 6
#define ND 256

typedef __attribute__((ext_vector_type(8))) short bf16x8;
typedef __attribute__((ext_vector_type(4))) float f32x4;

__device__ __forceinline__ float bf2f(uint16_t u) {
  return __uint_as_float(((uint32_t)u) << 16);
}
__device__ __forceinline__ uint16_t f2bf(float f) {
  uint32_t x = __float_as_uint(f);
  x += 0x7FFFu + ((x >> 16) & 1u);
  return (uint16_t)(x >> 16);
}

// ---------------------------------------------------------------------------
// k_front: merged independent preprocessing.
//   blocks 0..10    : k_prep (adjacency/lists/midx) + ud2/us2 + bW1=bo@W1[c]
//   blocks 11..42   : k_prept (Wk/Wv transposes to bf16 N-major)
//   blocks 43..82   : FT[c] = (Wo @ W1[c])^T  (fused weight, MFMA)
//   blocks 83..338  : k_ruleq (rule embeddings + Q proj, bf16*0.125)
//   blocks 339..2386: k_kvproj (KX/VX = vis @ Wk/Wv + bias, MFMA)
// ---------------------------------------------------------------------------
__global__ __launch_bounds__(256) void k_front(
    const void* __restrict__ adj_raw, const int* __restrict__ mask,
    const float* __restrict__ W2, const float* __restrict__ a2s,
    const float* __restrict__ a2d,
    uint32_t* __restrict__ adjbits, int* __restrict__ cls,
    int* __restrict__ lists, int* __restrict__ cnt,
    int* __restrict__ deg, uint8_t* __restrict__ nbr,
    int8_t* __restrict__ midx,
    float* __restrict__ ud2, float* __restrict__ us2,
    const float* __restrict__ Wo, const float* __restrict__ Wk,
    const float* __restrict__ Wv, const float* __restrict__ W1,
    const float* __restrict__ bo,
    uint16_t* __restrict__ WKVT, uint16_t* __restrict__ FT,
    float* __restrict__ BW1,
    const float* __restrict__ basic, const float* __restrict__ cruc,
    const float* __restrict__ Wtb, const float* __restrict__ btb,
    const float* __restrict__ Wtk, const float* __restrict__ btk,
    const float* __restrict__ Wq, const float* __restrict__ bq,
    uint16_t* __restrict__ Qbf,
    const float* __restrict__ vis, const float* __restrict__ bk,
    const float* __restrict__ bv,
    uint16_t* __restrict__ KX, uint16_t* __restrict__ VX)
{
  __shared__ char smem[33792];
  int bid = blockIdx.x;
  int tid = threadIdx.x;
  if (bid < 11) {
    // ---- k_prep ----
    if (bid == 0) {
      int* s_is4 = (int*)smem;
      if (tid == 0) *s_is4 = 1;
      __syncthreads();
      const uint32_t* u = (const uint32_t*)adj_raw;
      int ok = 1;
      for (int idx = tid; idx < 16384; idx += 256) {
        uint32_t v = u[idx];
        if (!(v == 0u || v == 1u || v == 0x3F800000u)) ok = 0;
      }
      if (!ok) atomicAnd(s_is4, 0);
      __syncthreads();
      int is4 = *s_is4;
      const uint8_t* b8 = (const uint8_t*)adj_raw;
      int dg = 0;
      for (int w = 0; w < 8; ++w) {
        uint32_t word = 0;
        for (int jb = 0; jb < 32; ++jb) {
          int j = w * 32 + jb;
          int bit = is4 ? (u[tid * 256 + j] != 0u) : (b8[tid * 256 + j] != 0);
          if (bit) {
            word |= (1u << jb);
            if (dg < 64) nbr[tid * 64 + dg] = (uint8_t)j;
            dg++;
          }
        }
        adjbits[tid * 8 + w] = word;
      }
      deg[tid] = (dg > 64) ? 64 : dg;
      int c = 0;
      for (int cc = 0; cc < NC; ++cc) if (mask[cc * 256 + tid] != 0) c = cc;
      cls[tid] = c;
      __syncthreads();
      if (tid == 0) {
        int cn[NC];
        for (int i = 0; i < NC; ++i) cn[i] = 0;
        for (int r = 0; r < 256; ++r) {
          int cc = cls[r];
          if (cn[cc] < 64) lists[cc * 64 + cn[cc]] = r;
          cn[cc]++;
        }
        for (int i = 0; i < NC; ++i) cnt[i] = (cn[i] > 64) ? 64 : cn[i];
        for (int i = 0; i < NC * 256; ++i) midx[i] = -1;
        for (int cc = 0; cc < NC; ++cc)
          for (int i = 0; i < cnt[cc]; ++i)
            midx[cc * 256 + lists[cc * 64 + i]] = (int8_t)i;
      }
    } else {
      int c = bid - 1;
      if (tid < 128) {
        float s1 = 0.f, s2 = 0.f;
        for (int g = 0; g < 64; ++g) {
          float w = W2[(c * 128 + tid) * 64 + g];
          s1 += w * a2d[c * 64 + g];
          s2 += w * a2s[c * 64 + g];
        }
        ud2[c * 128 + tid] = s1;
        us2[c * 128 + tid] = s2;
        float s3 = 0.f;
        for (int m = 0; m < 256; ++m)
          s3 += bo[m] * W1[(long)c * 32768 + m * 128 + tid];
        BW1[c * 128 + tid] = s3;
      }
    }
  } else if (bid < 43) {
    // ---- k_prept (Wk / Wv only) ----
    float (*ts)[65] = (float(*)[65])smem;
    int pb = bid - 11;
    const float* src;
    uint16_t* dst;
    int kt, nt;
    if (pb < 16)      { src = Wk; dst = WKVT; kt = pb >> 2; nt = pb & 3; }
    else { int t = pb - 16; src = Wv; dst = WKVT + 256 * 256; kt = t >> 2; nt = t & 3; }
    for (int idx = tid; idx < 4096; idx += 256) {
      int i = idx >> 6, j = idx & 63;
      ts[i][j] = src[(long)(kt * 64 + i) * 256 + nt * 64 + j];
    }
    __syncthreads();
    for (int idx = tid; idx < 4096; idx += 256) {
      int i = idx >> 6, j = idx & 63;
      dst[(long)(nt * 64 + i) * 256 + kt * 64 + j] = f2bf(ts[j][i]);
    }
  } else if (bid < 83) {
    // ---- FT[c] = (Wo @ W1[c])^T, MFMA, N-major bf16 output ----
    uint16_t* ts = (uint16_t*)smem;   // [128][72] bf16 = 18432 B
    int pb = bid - 43;
    int c = pb >> 2, mt = pb & 3;     // mt: 64-row k-tile of Wo
    int lane = tid & 63, w = tid >> 6;
    int r15 = lane & 15, kg = lane >> 4;
    int k0 = mt * 64;
    int colA = w * 32 + r15, colB = colA + 16;
    f32x4 acc[4][2];
    #pragma unroll
    for (int m2 = 0; m2 < 4; ++m2) {
      acc[m2][0] = (f32x4){0.f, 0.f, 0.f, 0.f};
      acc[m2][1] = (f32x4){0.f, 0.f, 0.f, 0.f};
    }
    for (int s4 = 0; s4 < 4; ++s4) {  // m-slices of 64
      __syncthreads();
      for (int idx = tid; idx < 8192; idx += 256) {
        int i = idx >> 7, nn = idx & 127;
        ts[nn * 72 + i] = f2bf(W1[(long)c * 32768 + (s4 * 64 + i) * 128 + nn]);
      }
      __syncthreads();
      #pragma unroll
      for (int kk = 0; kk < 2; ++kk) {
        bf16x8 bA = *(const bf16x8*)&ts[colA * 72 + kk * 32 + kg * 8];
        bf16x8 bB = *(const bf16x8*)&ts[colB * 72 + kk * 32 + kg * 8];
        #pragma unroll
        for (int m2 = 0; m2 < 4; ++m2) {
          const float* wp = &Wo[(long)(k0 + m2 * 16 + r15) * 256 + s4 * 64 + kk * 32 + kg * 8];
          float4 f0 = *(const float4*)wp, f1 = *(const float4*)(wp + 4);
          union { bf16x8 v; uint32_t u[4]; } af;
          af.u[0] = (uint32_t)f2bf(f0.x) | ((uint32_t)f2bf(f0.y) << 16);
          af.u[1] = (uint32_t)f2bf(f0.z) | ((uint32_t)f2bf(f0.w) << 16);
          af.u[2] = (uint32_t)f2bf(f1.x) | ((uint32_t)f2bf(f1.y) << 16);
          af.u[3] = (uint32_t)f2bf(f1.z) | ((uint32_t)f2bf(f1.w) << 16);
          acc[m2][0] = __builtin_amdgcn_mfma_f32_16x16x32_bf16(af.v, bA, acc[m2][0], 0, 0, 0);
          acc[m2][1] = __builtin_amdgcn_mfma_f32_16x16x32_bf16(af.v, bB, acc[m2][1], 0, 0, 0);
        }
      }
    }
    #pragma unroll
    for (int m2 = 0; m2 < 4; ++m2)
      #pragma unroll
      for (int j = 0; j < 4; ++j) {
        int k = k0 + m2 * 16 + kg * 4 + j;
        FT[(long)c * 32768 + colA * 256 + k] = f2bf(acc[m2][0][j]);
        FT[(long)c * 32768 + colB * 256 + k] = f2bf(acc[m2][1][j]);
      }
  } else if (bid < 339) {
    // ---- k_ruleq ----
    float* row_s  = (float*)smem;              // 2048 f
    float* rule_s = row_s + 2048;              // 256 f
    int*   nzi    = (int*)(rule_s + 256);      // 128 i
    float* nzv    = (float*)(nzi + 128);       // 128 f
    int*   nzcp   = (int*)(nzv + 128);         // 1 i
    int r = bid - 83;
    float acc = btb[tid] + btk[tid];
    for (int m = 0; m < 2; ++m) {
      const float* src = m ? cruc : basic;
      const float* W   = m ? Wtk : Wtb;
      for (int idx = tid; idx < 2048; idx += 256)
        row_s[idx] = (idx < NV) ? src[r * NV + idx] : 0.0f;
      if (tid == 0) *nzcp = 0;
      __syncthreads();
      if (tid < 64) {
        int base = 0;
        for (int ch = 0; ch < 32; ++ch) {
          int idx = ch * 64 + tid;
          float v = row_s[idx];
          unsigned long long bm = __ballot(v != 0.0f);
          if (v != 0.0f) {
            int pos = base + (int)__popcll(bm & ((1ull << tid) - 1ull));
            if (pos < 128) { nzi[pos] = idx; nzv[pos] = v; }
          }
          base += (int)__popcll(bm);
        }
        if (tid == 0) *nzcp = (base > 128) ? 128 : base;
      }
      __syncthreads();
      int n = *nzcp;
      for (int t = 0; t < n; ++t) acc += nzv[t] * W[nzi[t] * 256 + tid];
      __syncthreads();
    }
    rule_s[tid] = acc;
    __syncthreads();
    float q = bq[tid];
    for (int k2 = 0; k2 < 256; ++k2) q += rule_s[k2] * Wq[k2 * 256 + tid];
    Qbf[r * 256 + tid] = f2bf(q * 0.125f);
  } else {
    // ---- k_kvproj ----
    uint16_t* A_s = (uint16_t*)smem;  // 64 x 264
    int t = bid - 339;
    int bx = t & 255, by = t >> 8;
    int lane = tid & 63, w = tid >> 6;
    int r15 = lane & 15, kg = lane >> 4;
    long m0 = (long)bx * 64;
    int n0 = by * 64 + w * 16;
    for (int idx = tid; idx < 2048; idx += 256) {
      int r = idx >> 5, ch = idx & 31;
      const float4* p = (const float4*)&vis[(m0 + r) * 256 + ch * 8];
      float4 v0 = p[0], v1 = p[1];
      uint4 wd;
      wd.x = (uint32_t)f2bf(v0.x) | ((uint32_t)f2bf(v0.y) << 16);
      wd.y = (uint32_t)f2bf(v0.z) | ((uint32_t)f2bf(v0.w) << 16);
      wd.z = (uint32_t)f2bf(v1.x) | ((uint32_t)f2bf(v1.y) << 16);
      wd.w = (uint32_t)f2bf(v1.z) | ((uint32_t)f2bf(v1.w) << 16);
      *(uint4*)&A_s[r * 264 + ch * 8] = wd;
    }
    __syncthreads();
    const uint16_t* bptr = &WKVT[(long)(n0 + r15) * 256 + kg * 8];
    f32x4 acc[4];
    #pragma unroll
    for (int mt = 0; mt < 4; ++mt) acc[mt] = (f32x4){0.f, 0.f, 0.f, 0.f};
    #pragma unroll
    for (int ks = 0; ks < 8; ++ks) {
      bf16x8 bfr = *(const bf16x8*)(bptr + ks * 32);
      #pragma unroll
      for (int mt = 0; mt < 4; ++mt) {
        bf16x8 afr = *(const bf16x8*)&A_s[(mt * 16 + r15) * 264 + kg * 8 + ks * 32];
        acc[mt] = __builtin_amdgcn_mfma_f32_16x16x32_bf16(afr, bfr, acc[mt], 0, 0, 0);
      }
    }
    int col = n0 + r15;
    float bb = (col < 256) ? bk[col] : bv[col - 256];
    uint16_t* outp = (col < 256) ? KX : VX;
    int oc = (col < 256) ? col : col - 256;
    #pragma unroll
    for (int mt = 0; mt < 4; ++mt)
      #pragma unroll
      for (int j = 0; j < 4; ++j) {
        long row = m0 + mt * 16 + kg * 4 + j;
        outp[row * 256 + oc] = f2bf(acc[mt][j] + bb);
      }
  }
}

// ---------------------------------------------------------------------------
// k_attn (MFMA): block = (batch b, half of rules), 512 thr / 8 waves.
// Writes emb_pre (NO Wo projection — folded into k_gat's fused weights).
// ---------------------------------------------------------------------------
__global__ __launch_bounds__(512) void k_attn(const uint16_t* __restrict__ Qbf,
                         const uint16_t* __restrict__ KX, const uint16_t* __restrict__ VX,
                         uint16_t* __restrict__ EMB)
{
  __shared__ uint16_t p_s[128 * 72];
  __shared__ uint16_t vt_s[64 * 72];
  int tid = threadIdx.x;
  int lane = tid & 63, w = tid >> 6;   // 8 waves
  int r15 = lane & 15, kg = lane >> 4;
  int b = blockIdx.x >> 1;
  int rbase = (blockIdx.x & 1) * 128;
  for (int h = 0; h < 4; ++h) {
    __syncthreads();  // prev head's vt_s reads done
    for (int idx = tid; idx < 2048; idx += 512) {
      int s = idx >> 5, d2 = (idx & 31) * 2;
      uint32_t v = *(const uint32_t*)&VX[((long)(b * 64 + s)) * 256 + h * 64 + d2];
      vt_s[d2 * 72 + s] = (uint16_t)(v & 0xffff);
      vt_s[(d2 + 1) * 72 + s] = (uint16_t)(v >> 16);
    }
    __syncthreads();
    f32x4 sacc[4];
    #pragma unroll
    for (int nt = 0; nt < 4; ++nt) sacc[nt] = (f32x4){0.f, 0.f, 0.f, 0.f};
    #pragma unroll
    for (int ks = 0; ks < 2; ++ks) {
      bf16x8 afr = *(const bf16x8*)&Qbf[(long)(rbase + w * 16 + r15) * 256 + h * 64 + ks * 32 + kg * 8];
      #pragma unroll
      for (int nt = 0; nt < 4; ++nt) {
        bf16x8 bfr = *(const bf16x8*)&KX[((long)(b * 64 + nt * 16 + r15)) * 256 + h * 64 + ks * 32 + kg * 8];
        sacc[nt] = __builtin_amdgcn_mfma_f32_16x16x32_bf16(afr, bfr, sacc[nt], 0, 0, 0);
      }
    }
    #pragma unroll
    for (int j = 0; j < 4; ++j) {
      float m = sacc[0][j];
      #pragma unroll
      for (int nt = 1; nt < 4; ++nt) m = fmaxf(m, sacc[nt][j]);
      m = fmaxf(m, __shfl_xor(m, 1));
      m = fmaxf(m, __shfl_xor(m, 2));
      m = fmaxf(m, __shfl_xor(m, 4));
      m = fmaxf(m, __shfl_xor(m, 8));
      float pv[4];
      float sum = 0.f;
      #pragma unroll
      for (int nt = 0; nt < 4; ++nt) { pv[nt] = __expf(sacc[nt][j] - m); sum += pv[nt]; }
      sum += __shfl_xor(sum, 1);
      sum += __shfl_xor(sum, 2);
      sum += __shfl_xor(sum, 4);
      sum += __shfl_xor(sum, 8);
      float rs = 1.0f / sum;
      #pragma unroll
      for (int nt = 0; nt < 4; ++nt)
        p_s[(w * 16 + kg * 4 + j) * 72 + nt * 16 + r15] = f2bf(pv[nt] * rs);
    }
    f32x4 oacc[4];
    #pragma unroll
    for (int nt = 0; nt < 4; ++nt) oacc[nt] = (f32x4){0.f, 0.f, 0.f, 0.f};
    #pragma unroll
    for (int ks = 0; ks < 2; ++ks) {
      bf16x8 afr = *(const bf16x8*)&p_s[(w * 16 + r15) * 72 + ks * 32 + kg * 8];
      #pragma unroll
      for (int nt = 0; nt < 4; ++nt) {
        bf16x8 bfr = *(const bf16x8*)&vt_s[(nt * 16 + r15) * 72 + ks * 32 + kg * 8];
        oacc[nt] = __builtin_amdgcn_mfma_f32_16x16x32_bf16(afr, bfr, oacc[nt], 0, 0, 0);
      }
    }
    #pragma unroll
    for (int nt = 0; nt < 4; ++nt)
      #pragma unroll
      for (int j = 0; j < 4; ++j) {
        long row = (long)(b * 256 + rbase + w * 16 + kg * 4 + j);
        EMB[row * 256 + h * 64 + nt * 16 + r15] = f2bf(oacc[nt][j]);
      }
  }
}

// ---------------------------------------------------------------------------
// k_gat v6: TWO batches per block; hW1 computed from emb_pre with FUSED
// weights FT = (Wo@W1[c])^T and bias bW1 = bo@W1[c] (k_wo deleted).
// ---------------------------------------------------------------------------
__global__ __launch_bounds__(1024) void k_gat(
    const uint16_t* __restrict__ EMB, const uint16_t* __restrict__ FT,
    const float* __restrict__ BW1,
    const float* __restrict__ a1d, const float* __restrict__ a1s,
    const int* __restrict__ lists, const int* __restrict__ cnt_g,
    const int* __restrict__ deg_g, const uint8_t* __restrict__ nbr_g,
    const int8_t* __restrict__ midx_g,
    const float* __restrict__ b1, const float* __restrict__ ud2_g,
    const float* __restrict__ us2_g, const float* __restrict__ W2,
    const float* __restrict__ b2, const float* __restrict__ Wl,
    const float* __restrict__ bl, float* __restrict__ out)
{
  __shared__ uint16_t alphaA[256 * 72], alphaB[256 * 72]; // later: tpartA/B
  __shared__ uint16_t hwtA[128 * 72], hwtB[128 * 72];     // later: svec/lvec
  __shared__ float e1dA_s[256], e1sA_s[256], e1dB_s[256], e1sB_s[256];
  __shared__ float rd1A_s[256], rd1B_s[256];              // later: wjA/wjB
  __shared__ float e2dA_s[256], e2sA_s[256], e2dB_s[256], e2sB_s[256];
  __shared__ float rd2A_s[256], rd2B_s[256];
  __shared__ float a1d_s[128], a1s_s[128], b1_s[128], ud2_s[128], us2_s[128];
  __shared__ float bw1_s[128];
  __shared__ float t_sA[128], t_sB[128];
  __shared__ int   list_s[64];
  __shared__ int8_t midx_s[256];
  float (*tpartA)[128] = (float(*)[128])alphaA;
  float (*tpartB)[128] = (float(*)[128])alphaB;
  float* wjA_s = rd1A_s;
  float* wjB_s = rd1B_s;
  float* svecA = (float*)hwtA;
  float* lvecA = (float*)(hwtA + 256);
  float* svecB = (float*)hwtB;
  float* lvecB = (float*)(hwtB + 256);
  int tid = threadIdx.x;
  int lane = tid & 63, w = tid >> 6;
  int r15 = lane & 15, kg = lane >> 4;
  int c = blockIdx.x >> 7, bp = blockIdx.x & 127;
  int bA = bp * 2, bB = bp * 2 + 1;
  int n = cnt_g[c];
  if (tid < 64) list_s[tid] = (tid < n) ? lists[c * 64 + tid] : 0;
  if (tid >= 64 && tid < 128) {
    int i = tid - 64;
    ((uint32_t*)midx_s)[i] = ((const uint32_t*)(midx_g + (long)c * 256))[i];
  }
  if (tid < 128) {
    a1d_s[tid] = a1d[c * 128 + tid];
    a1s_s[tid] = a1s[c * 128 + tid];
    b1_s[tid]  = b1[c * 128 + tid];
    ud2_s[tid] = ud2_g[c * 128 + tid];
    us2_s[tid] = us2_g[c * 128 + tid];
    bw1_s[tid] = BW1[c * 128 + tid];
  }
  if (tid < 256) {
    e1dA_s[tid] = 0.f; e1sA_s[tid] = 0.f;
    e1dB_s[tid] = 0.f; e1sB_s[tid] = 0.f;
  }
  // neighbor chunk prefetch: thread (r,q) owns neighbors [q*16, q*16+16)
  int r = tid >> 2, q = tid & 3;
  int dg = deg_g[r];
  int t0 = q * 16;
  int ncnt = dg - t0; ncnt = (ncnt < 0) ? 0 : (ncnt > 16 ? 16 : ncnt);
  const uint32_t* np = (const uint32_t*)&nbr_g[r * 64 + t0];
  uint32_t nbw0 = np[0], nbw1 = np[1], nbw2 = np[2], nbw3 = np[3];
  __syncthreads();  // B0
  // P2: hW1 MFMA for both batches; FT b-frags shared.
  int mt = w & 3, nh = w >> 2;
  int colA = nh * 32 + r15, colB = colA + 16;
  const uint16_t* bptr = &FT[((long)c * 128 + colA) * 256 + kg * 8];
  const uint16_t* arA = &EMB[((long)bA * 256 + list_s[mt * 16 + r15]) * 256 + kg * 8];
  const uint16_t* arB = &EMB[((long)bB * 256 + list_s[mt * 16 + r15]) * 256 + kg * 8];
  f32x4 aA0 = (f32x4){0.f,0.f,0.f,0.f}, aA1 = (f32x4){0.f,0.f,0.f,0.f};
  f32x4 aB0 = (f32x4){0.f,0.f,0.f,0.f}, aB1 = (f32x4){0.f,0.f,0.f,0.f};
  if (mt * 16 < n) {
    #pragma unroll
    for (int ks = 0; ks < 8; ++ks) {
      bf16x8 b0 = *(const bf16x8*)(bptr + ks * 32);
      bf16x8 b1f = *(const bf16x8*)(bptr + 16 * 256 + ks * 32);
      bf16x8 afA = *(const bf16x8*)(arA + ks * 32);
      bf16x8 afB = *(const bf16x8*)(arB + ks * 32);
      aA0 = __builtin_amdgcn_mfma_f32_16x16x32_bf16(afA, b0, aA0, 0, 0, 0);
      aA1 = __builtin_amdgcn_mfma_f32_16x16x32_bf16(afA, b1f, aA1, 0, 0, 0);
      aB0 = __builtin_amdgcn_mfma_f32_16x16x32_bf16(afB, b0, aB0, 0, 0, 0);
      aB1 = __builtin_amdgcn_mfma_f32_16x16x32_bf16(afB, b1f, aB1, 0, 0, 0);
    }
  }
  // P3: add fused bias; write hwt (transposed bf16) + pd/ps dots -> e2 temps
  {
    float bwA = bw1_s[colA], bwB = bw1_s[colB];
    #pragma unroll
    for (int j = 0; j < 4; ++j) {
      aA0[j] += bwA; aA1[j] += bwB;
      aB0[j] += bwA; aB1[j] += bwB;
    }
    uint2 pk;
    pk.x = (uint32_t)f2bf(aA0[0]) | ((uint32_t)f2bf(aA0[1]) << 16);
    pk.y = (uint32_t)f2bf(aA0[2]) | ((uint32_t)f2bf(aA0[3]) << 16);
    *(uint2*)&hwtA[colA * 72 + mt * 16 + kg * 4] = pk;
    pk.x = (uint32_t)f2bf(aA1[0]) | ((uint32_t)f2bf(aA1[1]) << 16);
    pk.y = (uint32_t)f2bf(aA1[2]) | ((uint32_t)f2bf(aA1[3]) << 16);
    *(uint2*)&hwtA[colB * 72 + mt * 16 + kg * 4] = pk;
    pk.x = (uint32_t)f2bf(aB0[0]) | ((uint32_t)f2bf(aB0[1]) << 16);
    pk.y = (uint32_t)f2bf(aB0[2]) | ((uint32_t)f2bf(aB0[3]) << 16);
    *(uint2*)&hwtB[colA * 72 + mt * 16 + kg * 4] = pk;
    pk.x = (uint32_t)f2bf(aB1[0]) | ((uint32_t)f2bf(aB1[1]) << 16);
    pk.y = (uint32_t)f2bf(aB1[2]) | ((uint32_t)f2bf(aB1[3]) << 16);
    *(uint2*)&hwtB[colB * 72 + mt * 16 + kg * 4] = pk;
    float adA = a1d_s[colA], adB = a1d_s[colB];
    float asA = a1s_s[colA], asB = a1s_s[colB];
    #pragma unroll
    for (int j = 0; j < 4; ++j) {
      float pdA = aA0[j] * adA + aA1[j] * adB;
      float psA = aA0[j] * asA + aA1[j] * asB;
      float pdB = aB0[j] * adA + aB1[j] * adB;
      float psB = aB0[j] * asA + aB1[j] * asB;
      pdA += __shfl_xor(pdA, 1); pdA += __shfl_xor(pdA, 2);
      pdA += __shfl_xor(pdA, 4); pdA += __shfl_xor(pdA, 8);
      psA += __shfl_xor(psA, 1); psA += __shfl_xor(psA, 2);
      psA += __shfl_xor(psA, 4); psA += __shfl_xor(psA, 8);
      pdB += __shfl_xor(pdB, 1); pdB += __shfl_xor(pdB, 2);
      pdB += __shfl_xor(pdB, 4); pdB += __shfl_xor(pdB, 8);
      psB += __shfl_xor(psB, 1); psB += __shfl_xor(psB, 2);
      psB += __shfl_xor(psB, 4); psB += __shfl_xor(psB, 8);
      if (r15 == 0) {
        int jm = mt * 16 + kg * 4 + j;
        e2dA_s[nh * 64 + jm] = pdA;
        e2sA_s[nh * 64 + jm] = psA;
        e2dB_s[nh * 64 + jm] = pdB;
        e2sB_s[nh * 64 + jm] = psB;
      }
    }
  }
  __syncthreads();  // B1
  // P4: zero own alpha row slices; combine e1d/e1s for members
  {
    uint32_t* zA = (uint32_t*)&alphaA[r * 72 + q * 18];
    uint32_t* zB = (uint32_t*)&alphaB[r * 72 + q * 18];
    #pragma unroll
    for (int i = 0; i < 9; ++i) { zA[i] = 0u; zB[i] = 0u; }
  }
  if (tid < 64 && tid < n) {
    float sdA = e2dA_s[tid] + e2dA_s[tid + 64] + e2dA_s[tid + 128] + e2dA_s[tid + 192];
    float ssA = e2sA_s[tid] + e2sA_s[tid + 64] + e2sA_s[tid + 128] + e2sA_s[tid + 192];
    float sdB = e2dB_s[tid] + e2dB_s[tid + 64] + e2dB_s[tid + 128] + e2dB_s[tid + 192];
    float ssB = e2sB_s[tid] + e2sB_s[tid + 64] + e2sB_s[tid + 128] + e2sB_s[tid + 192];
    int rr = list_s[tid];
    e1dA_s[rr] = sdA; e1sA_s[rr] = ssA;
    e1dB_s[rr] = sdB; e1sB_s[rr] = ssB;
  }
  __syncthreads();  // B2
  // P5: alpha scatter + den1 (both batches; register neighbor chunk)
  {
    float e1dAv = e1dA_s[r], e1dBv = e1dB_s[r];
    float denA = 0.f, denB = 0.f;
    #define NB_CHUNK(WORD, BASE)                                            \
      _Pragma("unroll")                                                     \
      for (int ii = 0; ii < 4; ++ii) {                                      \
        if (BASE + ii < ncnt) {                                             \
          int j = (int)((WORD >> (ii * 8)) & 255u);                         \
          float eA = e1dAv + e1sA_s[j];                                     \
          eA = fmaxf(eA, 0.2f * eA); eA = fminf(eA, 60.f);                  \
          float wA = __expf(eA); denA += wA;                                \
          float eB = e1dBv + e1sB_s[j];                                     \
          eB = fmaxf(eB, 0.2f * eB); eB = fminf(eB, 60.f);                  \
          float wB = __expf(eB); denB += wB;                                \
          int mi = midx_s[j];                                               \
          if (mi >= 0) {                                                    \
            alphaA[r * 72 + mi] = f2bf(wA);                                 \
            alphaB[r * 72 + mi] = f2bf(wB);                                 \
          }                                                                 \
        }                                                                   \
      }
    NB_CHUNK(nbw0, 0) NB_CHUNK(nbw1, 4) NB_CHUNK(nbw2, 8) NB_CHUNK(nbw3, 12)
    #undef NB_CHUNK
    denA += __shfl_xor(denA, 1); denA += __shfl_xor(denA, 2);
    denB += __shfl_xor(denB, 1); denB += __shfl_xor(denB, 2);
    if (q == 0) { rd1A_s[r] = 1.0f / denA; rd1B_s[r] = 1.0f / denB; }
  }
  __syncthreads();  // B3
  // P6: G = alpha @ hwt via MFMA, both batches. wave w -> rules w*16..+15.
  f32x4 gA[8], gB[8];
  #pragma unroll
  for (int nt = 0; nt < 8; ++nt) {
    gA[nt] = (f32x4){0.f, 0.f, 0.f, 0.f};
    gB[nt] = (f32x4){0.f, 0.f, 0.f, 0.f};
  }
  int kslices = (n > 32) ? 2 : 1;
  for (int ks = 0; ks < kslices; ++ks) {
    bf16x8 afA = *(const bf16x8*)&alphaA[(w * 16 + r15) * 72 + ks * 32 + kg * 8];
    bf16x8 afB = *(const bf16x8*)&alphaB[(w * 16 + r15) * 72 + ks * 32 + kg * 8];
    #pragma unroll
    for (int nt = 0; nt < 8; ++nt) {
      bf16x8 bfA = *(const bf16x8*)&hwtA[(nt * 16 + r15) * 72 + ks * 32 + kg * 8];
      bf16x8 bfB = *(const bf16x8*)&hwtB[(nt * 16 + r15) * 72 + ks * 32 + kg * 8];
      gA[nt] = __builtin_amdgcn_mfma_f32_16x16x32_bf16(afA, bfA, gA[nt], 0, 0, 0);
      gB[nt] = __builtin_amdgcn_mfma_f32_16x16x32_bf16(afB, bfB, gB[nt], 0, 0, 0);
    }
  }
  // P7: epilogue both batches: g = relu(G*rd1 + b1); e2 dots
  {
    float rdA[4], rdB[4];
    #pragma unroll
    for (int j = 0; j < 4; ++j) {
      rdA[j] = rd1A_s[w * 16 + kg * 4 + j];
      rdB[j] = rd1B_s[w * 16 + kg * 4 + j];
    }
    float edA[4] = {0.f,0.f,0.f,0.f}, esA[4] = {0.f,0.f,0.f,0.f};
    float edB[4] = {0.f,0.f,0.f,0.f}, esB[4] = {0.f,0.f,0.f,0.f};
    #pragma unroll
    for (int nt = 0; nt < 8; ++nt) {
      float uf = ud2_s[nt * 16 + r15], sf = us2_s[nt * 16 + r15];
      float bf = b1_s[nt * 16 + r15];
      #pragma unroll
      for (int j = 0; j < 4; ++j) {
        float gvA = fmaxf(gA[nt][j] * rdA[j] + bf, 0.f);
        gA[nt][j] = gvA;
        edA[j] += gvA * uf; esA[j] += gvA * sf;
        float gvB = fmaxf(gB[nt][j] * rdB[j] + bf, 0.f);
        gB[nt][j] = gvB;
        edB[j] += gvB * uf; esB[j] += gvB * sf;
      }
    }
    #pragma unroll
    for (int j = 0; j < 4; ++j) {
      edA[j] += __shfl_xor(edA[j], 1); edA[j] += __shfl_xor(edA[j], 2);
      edA[j] += __shfl_xor(edA[j], 4); edA[j] += __shfl_xor(edA[j], 8);
      esA[j] += __shfl_xor(esA[j], 1); esA[j] += __shfl_xor(esA[j], 2);
      esA[j] += __shfl_xor(esA[j], 4); esA[j] += __shfl_xor(esA[j], 8);
      edB[j] += __shfl_xor(edB[j], 1); edB[j] += __shfl_xor(edB[j], 2);
      edB[j] += __shfl_xor(edB[j], 4); edB[j] += __shfl_xor(edB[j], 8);
      esB[j] += __shfl_xor(esB[j], 1); esB[j] += __shfl_xor(esB[j], 2);
      esB[j] += __shfl_xor(esB[j], 4); esB[j] += __shfl_xor(esB[j], 8);
      if (r15 == 0) {
        int rr = w * 16 + kg * 4 + j;
        e2dA_s[rr] = edA[j]; e2sA_s[rr] = esA[j];
        e2dB_s[rr] = edB[j]; e2sB_s[rr] = esB[j];
      }
    }
  }
  __syncthreads();  // B4
  // P8: den2 both batches
  {
    float e2dAv = e2dA_s[r], e2dBv = e2dB_s[r];
    float dnA = 0.f, dnB = 0.f;
    #define NB_CHUNK(WORD, BASE)                                            \
      _Pragma("unroll")                                                     \
      for (int ii = 0; ii < 4; ++ii) {                                      \
        if (BASE + ii < ncnt) {                                             \
          int j = (int)((WORD >> (ii * 8)) & 255u);                         \
          float eA = e2dAv + e2sA_s[j];                                     \
          eA = fmaxf(eA, 0.2f * eA); eA = fminf(eA, 60.f);                  \
          dnA += __expf(eA);                                                \
          float eB = e2dBv + e2sB_s[j];                                     \
          eB = fmaxf(eB, 0.2f * eB); eB = fminf(eB, 60.f);                  \
          dnB += __expf(eB);                                                \
        }                                                                   \
      }
    NB_CHUNK(nbw0, 0) NB_CHUNK(nbw1, 4) NB_CHUNK(nbw2, 8) NB_CHUNK(nbw3, 12)
    #undef NB_CHUNK
    dnA += __shfl_xor(dnA, 1); dnA += __shfl_xor(dnA, 2);
    dnB += __shfl_xor(dnB, 1); dnB += __shfl_xor(dnB, 2);
    if (q == 0) { rd2A_s[r] = 1.0f / dnA; rd2B_s[r] = 1.0f / dnB; }
  }
  __syncthreads();  // B5
  // P9: column weights wj[r] = sum_i alpha2[i,r], both batches
  {
    float e2sAv = e2sA_s[r], e2sBv = e2sB_s[r];
    float wjA = 0.f, wjB = 0.f;
    #define NB_CHUNK(WORD, BASE)                                            \
      _Pragma("unroll")                                                     \
      for (int ii = 0; ii < 4; ++ii) {                                      \
        if (BASE + ii < ncnt) {                                             \
          int i2 = (int)((WORD >> (ii * 8)) & 255u);                        \
          float eA = e2dA_s[i2] + e2sAv;                                    \
          eA = fmaxf(eA, 0.2f * eA); eA = fminf(eA, 60.f);                  \
          wjA += __expf(eA) * rd2A_s[i2];                                   \
          float eB = e2dB_s[i2] + e2sBv;                                    \
          eB = fmaxf(eB, 0.2f * eB); eB = fminf(eB, 60.f);                  \
          wjB += __expf(eB) * rd2B_s[i2];                                   \
        }                                                                   \
      }
    NB_CHUNK(nbw0, 0) NB_CHUNK(nbw1, 4) NB_CHUNK(nbw2, 8) NB_CHUNK(nbw3, 12)
    #undef NB_CHUNK
    wjA += __shfl_xor(wjA, 1); wjA += __shfl_xor(wjA, 2);
    wjB += __shfl_xor(wjB, 1); wjB += __shfl_xor(wjB, 2);
    if (q == 0) { wjA_s[r] = wjA; wjB_s[r] = wjB; }
  }
  __syncthreads();  // B6
  // P10: t partials from live fragments (tpart aliases alpha, dead now)
  {
    float wvA[4], wvB[4];
    #pragma unroll
    for (int j = 0; j < 4; ++j) {
      wvA[j] = wjA_s[w * 16 + kg * 4 + j];
      wvB[j] = wjB_s[w * 16 + kg * 4 + j];
    }
    #pragma unroll
    for (int nt = 0; nt < 8; ++nt) {
      float tpA = wvA[0]*gA[nt][0] + wvA[1]*gA[nt][1] + wvA[2]*gA[nt][2] + wvA[3]*gA[nt][3];
      float tpB = wvB[0]*gB[nt][0] + wvB[1]*gB[nt][1] + wvB[2]*gB[nt][2] + wvB[3]*gB[nt][3];
      tpA += __shfl_xor(tpA, 16); tpA += __shfl_xor(tpA, 32);
      tpB += __shfl_xor(tpB, 16); tpB += __shfl_xor(tpB, 32);
      if (kg == 0) {
        tpartA[w][nt * 16 + r15] = tpA;
        tpartB[w][nt * 16 + r15] = tpB;
      }
    }
  }
  __syncthreads();  // B7
  // P11: t combine (thread halves)
  if (tid < 128) {
    float s = 0.f;
    #pragma unroll
    for (int w2 = 0; w2 < 16; ++w2) s += tpartA[w2][tid];
    t_sA[tid] = s;
  } else if (tid < 256) {
    int f = tid - 128;
    float s = 0.f;
    #pragma unroll
    for (int w2 = 0; w2 < 16; ++w2) s += tpartB[w2][f];
    t_sB[f] = s;
  }
  __syncthreads();  // B8
  // P12: svec partials: 512 threads per batch, coalesced W2 reads.
  {
    int batch = tid >> 9;
    int tt = tid & 511;
    int col = tt & 63, fg = tt >> 6;  // fg 0..7, 16 f each
    const float* tsrc = batch ? t_sB : t_sA;
    float sp = 0.f;
    #pragma unroll
    for (int i = 0; i < 16; ++i) {
      int f = fg * 16 + i;
      sp += tsrc[f] * W2[((long)c * 128 + f) * 64 + col];
    }
    if (batch) tpartB[fg][col] = sp; else tpartA[fg][col] = sp;
  }
  __syncthreads();  // B9
  if (tid < 64) {
    float s = 256.0f * b2[c * 64 + tid];
    #pragma unroll
    for (int fg = 0; fg < 8; ++fg) s += tpartA[fg][tid];
    svecA[tid] = s;
  } else if (tid >= 512 && tid < 576) {
    int col = tid - 512;
    float s = 256.0f * b2[c * 64 + col];
    #pragma unroll
    for (int fg = 0; fg < 8; ++fg) s += tpartB[fg][col];
    svecB[col] = s;
  }
  __syncthreads();  // B10
  if (tid < 6) {
    float lg = 256.0f * bl[c * 6 + tid];
    for (int f = 0; f < 64; ++f) lg += svecA[f] * Wl[((long)c * 64 + f) * 6 + tid];
    lvecA[tid] = lg;
  } else if (tid >= 512 && tid < 518) {
    int k = tid - 512;
    float lg = 256.0f * bl[c * 6 + k];
    for (int f = 0; f < 64; ++f) lg += svecB[f] * Wl[((long)c * 64 + f) * 6 + k];
    lvecB[k] = lg;
  }
  __syncthreads();  // B11
  if (tid == 0) {
    float mm = lvecA[0];
    for (int k2 = 1; k2 < 6; ++k2) mm = fmaxf(mm, lvecA[k2]);
    float ss = 0.f;
    for (int k2 = 0; k2 < 6; ++k2) ss += __expf(lvecA[k2] - mm);
    float lse = mm + __logf(ss);
    for (int k2 = 0; k2 < 6; ++k2) out[((long)c * 256 + bA) * 6 + k2] = lvecA[k2] - lse;
  } else if (tid == 512) {
    float mm = lvecB[0];
    for (int k2 = 1; k2 < 6; ++k2) mm = fmaxf(mm, lvecB[k2]);
    float ss = 0.f;
    for (int k2 = 0; k2 < 6; ++k2) ss += __expf(lvecB[k2] - mm);
    float lse = mm + __logf(ss);
    for (int k2 = 0; k2 < 6; ++k2) out[((long)c * 256 + bB) * 6 + k2] = lvecB[k2] - lse;
  }
}

// ---------------------------------------------------------------------------
extern "C" void kernel_launch(void* const* d_in, const int* in_sizes, int n_in,
                              void* d_out, int out_size, void* d_ws, size_t ws_size,
                              hipStream_t stream)
{
  const float* vis   = (const float*)d_in[0];
  const float* basic = (const float*)d_in[1];
  const float* cruc  = (const float*)d_in[2];
  const float* Wtb   = (const float*)d_in[3];
  const float* btb   = (const float*)d_in[4];
  const float* Wtk   = (const float*)d_in[5];
  const float* btk   = (const float*)d_in[6];
  const float* Wq    = (const float*)d_in[7];
  const float* bq    = (const float*)d_in[8];
  const float* Wk    = (const float*)d_in[9];
  const float* bk    = (const float*)d_in[10];
  const float* Wv    = (const float*)d_in[11];
  const float* bv    = (const float*)d_in[12];
  const float* Wo    = (const float*)d_in[13];
  const float* bo    = (const float*)d_in[14];
  const float* W1    = (const float*)d_in[15];
  const float* a1s   = (const float*)d_in[16];
  const float* a1d   = (const float*)d_in[17];
  const float* b1    = (const float*)d_in[18];
  const float* W2    = (const float*)d_in[19];
  const float* a2s   = (const float*)d_in[20];
  const float* a2d   = (const float*)d_in[21];
  const float* b2    = (const float*)d_in[22];
  const float* Wl    = (const float*)d_in[23];
  const float* bl    = (const float*)d_in[24];
  const void*  adj   = d_in[25];
  const int*   mask  = (const int*)d_in[26];
  float* out = (float*)d_out;
  char* ws = (char*)d_ws;

  uint16_t* QBF  = (uint16_t*)(ws + 0);         // 131072
  uint32_t* ADJ  = (uint32_t*)(ws + 262144);    // 8192
  int*      CLS  = (int*)(ws + 270336);         // 1024
  int*      LST  = (int*)(ws + 271360);         // 2560
  int*      CNT  = (int*)(ws + 273920);         // 64
  int*      DEG  = (int*)(ws + 273984);         // 1024
  uint8_t*  NBR  = (uint8_t*)(ws + 275008);     // 16384
  int8_t*   MIDX = (int8_t*)(ws + 291392);      // 2560
  float*    UD2  = (float*)(ws + 293952);       // 5120
  float*    US2  = (float*)(ws + 299072);       // 5120
  float*    BW1  = (float*)(ws + 304192);       // 5120
  uint16_t* WKVT = (uint16_t*)(ws + 435264);    // 262144
  uint16_t* FT   = (uint16_t*)(ws + 697408);    // 655360
  uint16_t* KX   = (uint16_t*)(ws + 1352768);   // 8388608
  uint16_t* VX   = (uint16_t*)(ws + 9741376);   // 8388608
  uint16_t* EMB  = (uint16_t*)(ws + 18129984);  // 33554432 -> total ~49.3 MiB

  hipLaunchKernelGGL(k_front, dim3(2387), dim3(256), 0, stream,
                     adj, mask, W2, a2s, a2d, ADJ, CLS, LST, CNT, DEG, NBR, MIDX,
                     UD2, US2,
                     Wo, Wk, Wv, W1, bo, WKVT, FT, BW1,
                     basic, cruc, Wtb, btb, Wtk, btk, Wq, bq, QBF,
                     vis, bk, bv, KX, VX);
  hipLaunchKernelGGL(k_attn, dim3(512), dim3(512), 0, stream, QBF, KX, VX, EMB);
  hipLaunchKernelGGL(k_gat, dim3(1280), dim3(1024), 0, stream,
                     EMB, FT, BW1, a1d, a1s, LST, CNT, DEG, NBR, MIDX,
                     b1, UD2, US2, W2, b2, Wl, bl, out);
}